// Round 3
// baseline (761.622 us; speedup 1.0000x reference)
//
#include <hip/hip_runtime.h>
#include <hip/hip_bf16.h>

#define B_    4
#define NUM   1024
#define CH    256
#define HEADS 4
#define DK    64

// ---------------- zero the topk union masks ----------------
__global__ void zero_vec_kernel(unsigned* v1, unsigned* v2) {
  int i = blockIdx.x * blockDim.x + threadIdx.x;
  if (i < NUM) { v1[i] = 0u; v2[i] = 0u; }
}

// ---------------- gts = relu(gt_feat @ gt_w^T + gt_b) ----------------
// M=4096 (b*n), N=256 (o), K=256. grid (64, 4), 256 thr, 64x64 tile, 4x4 micro.
__global__ __launch_bounds__(256) void gts_kernel(
    const float* __restrict__ gf, const float* __restrict__ gw,
    const float* __restrict__ gb, float* __restrict__ out) {
  __shared__ float As[64][65];
  __shared__ float Bs[64][65];
  const int m0 = blockIdx.x * 64, n0 = blockIdx.y * 64;
  const int tid = threadIdx.x, tx = tid & 15, ty = tid >> 4;
  float acc[4][4] = {};
  for (int k0 = 0; k0 < 256; k0 += 64) {
    __syncthreads();
    #pragma unroll
    for (int l = 0; l < 16; ++l) {
      int idx = tid + l * 256; int r = idx >> 6, c = idx & 63;
      As[r][c] = gf[(size_t)(m0 + r) * 256 + k0 + c];
      Bs[r][c] = gw[(size_t)(n0 + r) * 256 + k0 + c];
    }
    __syncthreads();
    #pragma unroll 8
    for (int k = 0; k < 64; ++k) {
      float av[4], bv[4];
      #pragma unroll
      for (int i = 0; i < 4; ++i) av[i] = As[ty * 4 + i][k];
      #pragma unroll
      for (int j = 0; j < 4; ++j) bv[j] = Bs[tx * 4 + j][k];
      #pragma unroll
      for (int i = 0; i < 4; ++i)
        #pragma unroll
        for (int j = 0; j < 4; ++j) acc[i][j] += av[i] * bv[j];
    }
  }
  #pragma unroll
  for (int i = 0; i < 4; ++i)
    #pragma unroll
    for (int j = 0; j < 4; ++j) {
      int o = n0 + tx * 4 + j;
      float v = acc[i][j] + gb[o];
      out[(size_t)(m0 + ty * 4 + i) * 256 + o] = fmaxf(v, 0.f);
    }
}

// ---------------- grouped 1x1 conv + relu, node-major ----------------
__global__ __launch_bounds__(256) void conv_kernel(
    const float* __restrict__ x, const float* __restrict__ w,
    const float* __restrict__ bias, float* __restrict__ out) {
  __shared__ float Xs[64][65];
  __shared__ float Wsm[64][65];
  const int m0 = blockIdx.x * 64, g = blockIdx.y;
  const int tid = threadIdx.x, tx = tid & 15, ty = tid >> 4;
  #pragma unroll
  for (int l = 0; l < 16; ++l) {
    int idx = tid + l * 256; int r = idx >> 6, c = idx & 63;
    Xs[r][c] = x[(size_t)(m0 + r) * CH + g * DK + c];
    Wsm[r][c] = w[g * DK * DK + r * DK + c];
  }
  __syncthreads();
  float acc[4][4] = {};
  #pragma unroll 8
  for (int k = 0; k < DK; ++k) {
    float av[4], bv[4];
    #pragma unroll
    for (int i = 0; i < 4; ++i) av[i] = Xs[ty * 4 + i][k];
    #pragma unroll
    for (int j = 0; j < 4; ++j) bv[j] = Wsm[tx * 4 + j][k];
    #pragma unroll
    for (int i = 0; i < 4; ++i)
      #pragma unroll
      for (int j = 0; j < 4; ++j) acc[i][j] += av[i] * bv[j];
  }
  #pragma unroll
  for (int i = 0; i < 4; ++i)
    #pragma unroll
    for (int j = 0; j < 4; ++j) {
      int o = g * DK + tx * 4 + j;
      float v = acc[i][j] + bias[o];
      out[(size_t)(m0 + ty * 4 + i) * CH + o] = fmaxf(v, 0.f);
    }
}

// ---------------- per-node per-head L2 norms ----------------
__global__ void norms_kernel(const float* __restrict__ x, float* __restrict__ nrm) {
  int bn = blockIdx.x;
  int t = threadIdx.x;
  float v = x[(size_t)bn * CH + t];
  float s = v * v;
  #pragma unroll
  for (int off = 32; off; off >>= 1) s += __shfl_down(s, off, 64);
  if ((t & 63) == 0) nrm[bn * HEADS + (t >> 6)] = sqrtf(s);
}

// top-4 insert, jax-stable tie-break (higher value first; equal value -> lower index)
__device__ inline void ins4(float v, int id, float tv[4], int tj[4]) {
  if (v < tv[3] || (v == tv[3] && id > tj[3])) return;
  tv[3] = v; tj[3] = id;
  #pragma unroll
  for (int k = 3; k > 0; --k) {
    bool sw = (tv[k] > tv[k - 1]) || (tv[k] == tv[k - 1] && tj[k] < tj[k - 1]);
    if (sw) {
      float fv = tv[k]; tv[k] = tv[k - 1]; tv[k - 1] = fv;
      int ti = tj[k]; tj[k] = tj[k - 1]; tj[k - 1] = ti;
    }
  }
}

// ---------------- per-row top-4 of cosine scores, union into vec ----------------
// LDS kept < 64 KB: the 64x64 merge arrays overlay the dead Xi/Xj tile buffers.
__global__ __launch_bounds__(256) void topk_kernel(
    const float* __restrict__ x, const float* __restrict__ nrm, unsigned* __restrict__ vec) {
  __shared__ float Xi[64 * 65];
  __shared__ float Xj[64 * 65];
  float* cV = Xi;                       // reused after j-loop (dead Xi)
  int* cI = (int*)Xj;                   // reused after j-loop (dead Xj)
  const int b = blockIdx.z, h = blockIdx.y, i0 = blockIdx.x * 64;
  const int tid = threadIdx.x, tx = tid & 15, ty = tid >> 4;
  #pragma unroll
  for (int l = 0; l < 16; ++l) {
    int idx = tid + l * 256; int r = idx >> 6, c = idx & 63;
    Xi[r * 65 + c] = x[(size_t)(b * NUM + i0 + r) * CH + h * DK + c];
  }
  float ni[4];
  #pragma unroll
  for (int ii = 0; ii < 4; ++ii) ni[ii] = nrm[(b * NUM + i0 + ty * 4 + ii) * HEADS + h];
  float tv[4][4]; int tj[4][4];
  #pragma unroll
  for (int ii = 0; ii < 4; ++ii)
    #pragma unroll
    for (int q = 0; q < 4; ++q) { tv[ii][q] = -1.f; tj[ii][q] = 0x7fffffff; }

  for (int j0 = 0; j0 < NUM; j0 += 64) {
    __syncthreads();
    #pragma unroll
    for (int l = 0; l < 16; ++l) {
      int idx = tid + l * 256; int r = idx >> 6, c = idx & 63;
      Xj[r * 65 + c] = x[(size_t)(b * NUM + j0 + r) * CH + h * DK + c];
    }
    __syncthreads();
    float acc[4][4] = {};
    #pragma unroll 8
    for (int k = 0; k < DK; ++k) {
      float av[4], bv[4];
      #pragma unroll
      for (int ii = 0; ii < 4; ++ii) av[ii] = Xi[(ty * 4 + ii) * 65 + k];
      #pragma unroll
      for (int jj = 0; jj < 4; ++jj) bv[jj] = Xj[(tx * 4 + jj) * 65 + k];
      #pragma unroll
      for (int ii = 0; ii < 4; ++ii)
        #pragma unroll
        for (int jj = 0; jj < 4; ++jj) acc[ii][jj] += av[ii] * bv[jj];
    }
    #pragma unroll
    for (int ii = 0; ii < 4; ++ii)
      #pragma unroll
      for (int jj = 0; jj < 4; ++jj) {
        int j = j0 + tx * 4 + jj;
        float nj = nrm[(b * NUM + j) * HEADS + h];
        float a = fmaxf(acc[ii][jj] / fmaxf(ni[ii] * nj, 1e-8f), 0.f);
        ins4(a, j, tv[ii], tj[ii]);
      }
  }
  __syncthreads();  // Xi/Xj dead; reuse as cV/cI
  #pragma unroll
  for (int ii = 0; ii < 4; ++ii)
    #pragma unroll
    for (int q = 0; q < 4; ++q) {
      cV[(ty * 4 + ii) * 64 + tx * 4 + q] = tv[ii][q];
      cI[(ty * 4 + ii) * 64 + tx * 4 + q] = tj[ii][q];
    }
  __syncthreads();
  if (tid < 64) {
    float fv[4] = {-1.f, -1.f, -1.f, -1.f};
    int fi[4] = {0x7fffffff, 0x7fffffff, 0x7fffffff, 0x7fffffff};
    for (int q = 0; q < 64; ++q) ins4(cV[tid * 64 + q], cI[tid * 64 + q], fv, fi);
    #pragma unroll
    for (int q = 0; q < 4; ++q) vec[fi[q]] = 1u;  // benign race, all write 1
  }
}

// ---------------- masked attention apply: om[i,c] = sum_j w_ij * conv[j,c] ----------------
// w_ij = (relu(cos_ij) * mroi_ij * sm_j * vec_j + (i==j && sm_i==0)) * 0.25
// LDS < 64 KB: Cv (conv tile) overlays Xj after the score phase of each tile.
__global__ __launch_bounds__(256) void apply_kernel(
    const float* __restrict__ x, const float* __restrict__ conv,
    const float* __restrict__ addsrc, float* __restrict__ out,
    const float* __restrict__ nrm, const unsigned* __restrict__ vec,
    const int* __restrict__ mroi, const int* __restrict__ smask) {
  __shared__ float Xi[64 * 65];
  __shared__ float Xj[64 * 65];   // holds x-tile for scores, then conv-tile for PV
  __shared__ float Sm[64 * 65];
  const int b = blockIdx.z, h = blockIdx.y, i0 = blockIdx.x * 64;
  const int tid = threadIdx.x, tx = tid & 15, ty = tid >> 4;
  #pragma unroll
  for (int l = 0; l < 16; ++l) {
    int idx = tid + l * 256; int r = idx >> 6, c = idx & 63;
    Xi[r * 65 + c] = x[(size_t)(b * NUM + i0 + r) * CH + h * DK + c];
  }
  float ni[4]; int smi[4];
  #pragma unroll
  for (int ii = 0; ii < 4; ++ii) {
    int row = i0 + ty * 4 + ii;
    ni[ii] = nrm[(b * NUM + row) * HEADS + h];
    smi[ii] = smask[b * NUM + row];
  }
  float om[4][4] = {};
  for (int j0 = 0; j0 < NUM; j0 += 64) {
    __syncthreads();
    #pragma unroll
    for (int l = 0; l < 16; ++l) {
      int idx = tid + l * 256; int r = idx >> 6, c = idx & 63;
      Xj[r * 65 + c] = x[(size_t)(b * NUM + j0 + r) * CH + h * DK + c];
    }
    __syncthreads();
    float acc[4][4] = {};
    #pragma unroll 8
    for (int k = 0; k < DK; ++k) {
      float av[4], bv[4];
      #pragma unroll
      for (int ii = 0; ii < 4; ++ii) av[ii] = Xi[(ty * 4 + ii) * 65 + k];
      #pragma unroll
      for (int jj = 0; jj < 4; ++jj) bv[jj] = Xj[(tx * 4 + jj) * 65 + k];
      #pragma unroll
      for (int ii = 0; ii < 4; ++ii)
        #pragma unroll
        for (int jj = 0; jj < 4; ++jj) acc[ii][jj] += av[ii] * bv[jj];
    }
    #pragma unroll
    for (int ii = 0; ii < 4; ++ii)
      #pragma unroll
      for (int jj = 0; jj < 4; ++jj) {
        int i = i0 + ty * 4 + ii, j = j0 + tx * 4 + jj;
        float nj = nrm[(b * NUM + j) * HEADS + h];
        float a = fmaxf(acc[ii][jj] / fmaxf(ni[ii] * nj, 1e-8f), 0.f);
        bool cond = (mroi[(size_t)(b * NUM + i) * NUM + j] != 0) &&
                    (smask[b * NUM + j] != 0) && (vec[j] != 0u);
        float wgt = cond ? a * 0.25f : 0.f;
        if (i == j && smi[ii] == 0) wgt += 0.25f;
        Sm[(ty * 4 + ii) * 65 + tx * 4 + jj] = wgt;
      }
    __syncthreads();  // scores done; Xj x-tile dead -> load conv tile into it
    #pragma unroll
    for (int l = 0; l < 16; ++l) {
      int idx = tid + l * 256; int r = idx >> 6, c = idx & 63;
      Xj[r * 65 + c] = conv[(size_t)(b * NUM + j0 + r) * CH + h * DK + c];
    }
    __syncthreads();
    #pragma unroll 8
    for (int jl = 0; jl < 64; ++jl) {
      float sv[4], cv[4];
      #pragma unroll
      for (int ii = 0; ii < 4; ++ii) sv[ii] = Sm[(ty * 4 + ii) * 65 + jl];
      #pragma unroll
      for (int cc = 0; cc < 4; ++cc) cv[cc] = Xj[jl * 65 + tx * 4 + cc];
      #pragma unroll
      for (int ii = 0; ii < 4; ++ii)
        #pragma unroll
        for (int cc = 0; cc < 4; ++cc) om[ii][cc] += sv[ii] * cv[cc];
    }
  }
  #pragma unroll
  for (int ii = 0; ii < 4; ++ii)
    #pragma unroll
    for (int cc = 0; cc < 4; ++cc) {
      size_t idx = (size_t)(b * NUM + i0 + ty * 4 + ii) * CH + h * DK + tx * 4 + cc;
      float v = om[ii][cc];
      if (addsrc) v += addsrc[idx];
      out[idx] = v;
    }
}

// ---------------- LayerNorm + final outputs (in-place on d_out regions) ----------------
// ybnf: in = Yb (o2m, node-major), out = node_feat. out0: in = X2 (conv2), out = X2 + nf.
__global__ __launch_bounds__(256) void final_kernel(
    float* __restrict__ ybnf, float* __restrict__ out0,
    const float* __restrict__ lnw, const float* __restrict__ lnb) {
  __shared__ float r1[4];
  __shared__ float r2[4];
  int bn = blockIdx.x;
  int c = threadIdx.x;
  size_t idx = (size_t)bn * CH + c;
  float y = ybnf[idx];
  float x2v = out0[idx];
  float s = y;
  #pragma unroll
  for (int off = 32; off; off >>= 1) s += __shfl_down(s, off, 64);
  int wave = c >> 6, lane = c & 63;
  if (lane == 0) r1[wave] = s;
  __syncthreads();
  float mu = (r1[0] + r1[1] + r1[2] + r1[3]) * (1.f / 256.f);
  float d = y - mu;
  float s2 = d * d;
  #pragma unroll
  for (int off = 32; off; off >>= 1) s2 += __shfl_down(s2, off, 64);
  if (lane == 0) r2[wave] = s2;
  __syncthreads();
  float var = (r2[0] + r2[1] + r2[2] + r2[3]) * (1.f / 256.f);
  float nf = d * rsqrtf(var + 1e-6f) * lnw[c] + lnb[c];
  ybnf[idx] = nf;
  out0[idx] = x2v + nf;
}

extern "C" void kernel_launch(void* const* d_in, const int* in_sizes, int n_in,
                              void* d_out, int out_size, void* d_ws, size_t ws_size,
                              hipStream_t stream) {
  const float* input = (const float*)d_in[0];
  const int* mroi = (const int*)d_in[1];
  const int* smask = (const int*)d_in[2];
  const float* gt_feat = (const float*)d_in[3];
  const float* w1 = (const float*)d_in[4];
  const float* b1 = (const float*)d_in[5];
  const float* w2 = (const float*)d_in[6];
  const float* b2 = (const float*)d_in[7];
  const float* gt_w = (const float*)d_in[8];
  const float* gt_b = (const float*)d_in[9];
  const float* lnw = (const float*)d_in[10];
  const float* lnb = (const float*)d_in[11];

  const size_t SEG = (size_t)B_ * NUM * CH;  // 1048576 elements
  float* out0 = (float*)d_out;     // finally: out2^T + node_feat ; interim: X2 (conv2)
  float* gts = out0 + SEG;         // gts output (final from the start)
  float* nfreg = out0 + 2 * SEG;   // finally: node_feat ; interim: X1 then Yb

  // workspace: F1 (fp32, 4 MB) + NRM (64 KB) + VEC1/VEC2 (8 KB) ~= 4.3 MB total
  float* F1 = (float*)d_ws;
  float* NRM = F1 + SEG;
  unsigned* VEC1 = (unsigned*)(NRM + (size_t)B_ * NUM * HEADS);
  unsigned* VEC2 = VEC1 + NUM;

  float* X1 = nfreg;  // conv1 output lives in node_feat region until apply1 consumes it
  float* X2 = out0;   // conv2 output lives in out0 region until final_kernel
  float* Yb = nfreg;  // o2m lives in node_feat region until final_kernel (X1 dead)

  zero_vec_kernel<<<4, 256, 0, stream>>>(VEC1, VEC2);
  gts_kernel<<<dim3(64, 4), 256, 0, stream>>>(gt_feat, gt_w, gt_b, gts);

  // stage 1
  conv_kernel<<<dim3(64, 4), 256, 0, stream>>>(input, w1, b1, X1);
  norms_kernel<<<4096, 256, 0, stream>>>(input, NRM);
  topk_kernel<<<dim3(16, HEADS, B_), 256, 0, stream>>>(input, NRM, VEC1);
  apply_kernel<<<dim3(16, HEADS, B_), 256, 0, stream>>>(
      input, X1, X1, F1, NRM, VEC1, mroi, smask);

  // stage 2
  conv_kernel<<<dim3(64, 4), 256, 0, stream>>>(F1, w2, b2, X2);
  norms_kernel<<<4096, 256, 0, stream>>>(F1, NRM);
  topk_kernel<<<dim3(16, HEADS, B_), 256, 0, stream>>>(F1, NRM, VEC2);
  apply_kernel<<<dim3(16, HEADS, B_), 256, 0, stream>>>(
      F1, X2, nullptr, Yb, NRM, VEC2, mroi, smask);

  final_kernel<<<4096, 256, 0, stream>>>(Yb, X2, lnw, lnb);
}

// Round 4
// 501.267 us; speedup vs baseline: 1.5194x; 1.5194x over previous
//
#include <hip/hip_runtime.h>
#include <hip/hip_bf16.h>

#define B_    4
#define NUM   1024
#define CH    256
#define HEADS 4
#define DK    64
#define LDK   72   // padded LDS row stride in bf16 elements (2-way bank alias = free)

typedef __hip_bfloat16 bf;
typedef __attribute__((ext_vector_type(8))) short short8;
typedef __attribute__((ext_vector_type(4))) float f32x4;

__device__ inline bf tobf(float v) { return __float2bfloat16(v); }

// ---------------- zero the topk union masks ----------------
__global__ void zero_vec_kernel(unsigned* v1, unsigned* v2) {
  int i = blockIdx.x * blockDim.x + threadIdx.x;
  if (i < NUM) { v1[i] = 0u; v2[i] = 0u; }
}

// stage a 64x64 fp32 global tile -> bf16 LDS tile [64][LDK]
__device__ inline void stage_tile(const float* __restrict__ src, size_t row0,
                                  int col0, int rowstride, bf (*dst)[LDK], int tid) {
  int r = tid >> 4, c4 = (tid & 15) * 4;
  #pragma unroll
  for (int it = 0; it < 4; ++it) {
    int row = r + it * 16;
    const float4 v = *(const float4*)&src[(row0 + row) * (size_t)rowstride + col0 + c4];
    union { bf h4[4]; short4 s4; } u;
    u.h4[0] = tobf(v.x); u.h4[1] = tobf(v.y); u.h4[2] = tobf(v.z); u.h4[3] = tobf(v.w);
    *(short4*)&dst[row][c4] = u.s4;
  }
}

// ---------------- gts = relu(gt_feat @ gt_w^T + gt_b), bf16 MFMA ----------------
__global__ __launch_bounds__(256) void gts_kernel(
    const float* __restrict__ gf, const float* __restrict__ gw,
    const float* __restrict__ gb, float* __restrict__ out) {
  __shared__ __align__(16) bf As[64][LDK];
  __shared__ __align__(16) bf Bs[64][LDK];
  const int m0 = blockIdx.x * 64, n0 = blockIdx.y * 64;
  const int tid = threadIdx.x, lane = tid & 63, w = tid >> 6;
  const int m = lane & 15, quad = lane >> 4;
  f32x4 acc[4] = {{0.f,0.f,0.f,0.f},{0.f,0.f,0.f,0.f},{0.f,0.f,0.f,0.f},{0.f,0.f,0.f,0.f}};
  for (int k0 = 0; k0 < 256; k0 += 64) {
    __syncthreads();
    stage_tile(gf, m0, k0, 256, As, tid);
    stage_tile(gw, n0, k0, 256, Bs, tid);
    __syncthreads();
    #pragma unroll
    for (int kb = 0; kb < 2; ++kb) {
      short8 a = *(const short8*)&As[w * 16 + m][kb * 32 + quad * 8];
      #pragma unroll
      for (int nt = 0; nt < 4; ++nt) {
        short8 bb = *(const short8*)&Bs[nt * 16 + m][kb * 32 + quad * 8];
        acc[nt] = __builtin_amdgcn_mfma_f32_16x16x32_bf16(a, bb, acc[nt], 0, 0, 0);
      }
    }
  }
  #pragma unroll
  for (int nt = 0; nt < 4; ++nt)
    #pragma unroll
    for (int r = 0; r < 4; ++r) {
      int row = m0 + w * 16 + quad * 4 + r, col = n0 + nt * 16 + m;
      out[(size_t)row * 256 + col] = fmaxf(acc[nt][r] + gb[col], 0.f);
    }
}

// ---------------- grouped 1x1 conv + relu (fp32, small) ----------------
__global__ __launch_bounds__(256) void conv_kernel(
    const float* __restrict__ x, const float* __restrict__ w,
    const float* __restrict__ bias, float* __restrict__ out) {
  __shared__ float Xs[64][65];
  __shared__ float Wsm[64][65];
  const int m0 = blockIdx.x * 64, g = blockIdx.y;
  const int tid = threadIdx.x, tx = tid & 15, ty = tid >> 4;
  #pragma unroll
  for (int l = 0; l < 16; ++l) {
    int idx = tid + l * 256; int r = idx >> 6, c = idx & 63;
    Xs[r][c] = x[(size_t)(m0 + r) * CH + g * DK + c];
    Wsm[r][c] = w[g * DK * DK + r * DK + c];
  }
  __syncthreads();
  float acc[4][4] = {};
  #pragma unroll 8
  for (int k = 0; k < DK; ++k) {
    float av[4], bv[4];
    #pragma unroll
    for (int i = 0; i < 4; ++i) av[i] = Xs[ty * 4 + i][k];
    #pragma unroll
    for (int j = 0; j < 4; ++j) bv[j] = Wsm[tx * 4 + j][k];
    #pragma unroll
    for (int i = 0; i < 4; ++i)
      #pragma unroll
      for (int j = 0; j < 4; ++j) acc[i][j] += av[i] * bv[j];
  }
  #pragma unroll
  for (int i = 0; i < 4; ++i)
    #pragma unroll
    for (int j = 0; j < 4; ++j) {
      int o = g * DK + tx * 4 + j;
      out[(size_t)(m0 + ty * 4 + i) * CH + o] = fmaxf(acc[i][j] + bias[o], 0.f);
    }
}

// ---------------- per-node per-head L2 norms ----------------
__global__ void norms_kernel(const float* __restrict__ x, float* __restrict__ nrm) {
  int bn = blockIdx.x;
  int t = threadIdx.x;
  float v = x[(size_t)bn * CH + t];
  float s = v * v;
  #pragma unroll
  for (int off = 32; off; off >>= 1) s += __shfl_down(s, off, 64);
  if ((t & 63) == 0) nrm[bn * HEADS + (t >> 6)] = sqrtf(s);
}

// top-4 insert, jax-stable tie-break (higher value first; equal value -> lower index)
__device__ inline void ins4(float v, int id, float tv[4], int tj[4]) {
  if (v < tv[3] || (v == tv[3] && id > tj[3])) return;
  tv[3] = v; tj[3] = id;
  #pragma unroll
  for (int k = 3; k > 0; --k) {
    bool sw = (tv[k] > tv[k - 1]) || (tv[k] == tv[k - 1] && tj[k] < tj[k - 1]);
    if (sw) {
      float fv = tv[k]; tv[k] = tv[k - 1]; tv[k - 1] = fv;
      int ti = tj[k]; tj[k] = tj[k - 1]; tj[k - 1] = ti;
    }
  }
}

// ---------------- per-row top-4 of cosine scores (bf16 MFMA), union into vec ----------------
__global__ __launch_bounds__(256) void topk_kernel(
    const float* __restrict__ x, const float* __restrict__ nrm, unsigned* __restrict__ vec) {
  __shared__ __align__(16) bf Ai[64][LDK];
  __shared__ __align__(16) bf Xj[64][LDK];
  __shared__ float cV[64][64];
  __shared__ int cI[64][64];
  const int b = blockIdx.z, h = blockIdx.y, i0 = blockIdx.x * 64;
  const int tid = threadIdx.x, lane = tid & 63, w = tid >> 6;
  const int m = lane & 15, quad = lane >> 4;

  stage_tile(x, (size_t)b * NUM + i0, h * DK, CH, Ai, tid);
  float ni[4];
  #pragma unroll
  for (int r = 0; r < 4; ++r)
    ni[r] = nrm[((size_t)b * NUM + i0 + w * 16 + quad * 4 + r) * HEADS + h];

  float tv[4][4]; int tj[4][4];
  #pragma unroll
  for (int r = 0; r < 4; ++r)
    #pragma unroll
    for (int q = 0; q < 4; ++q) { tv[r][q] = -1.f; tj[r][q] = 0x7fffffff; }

  for (int j0 = 0; j0 < NUM; j0 += 64) {
    __syncthreads();
    stage_tile(x, (size_t)b * NUM + j0, h * DK, CH, Xj, tid);
    __syncthreads();
    #pragma unroll
    for (int kb = 0; kb < 2; ++kb) {
      // hoisted A frags are CSE'd by compiler; keep simple form
    }
    #pragma unroll
    for (int nt = 0; nt < 4; ++nt) {
      f32x4 acc = {0.f, 0.f, 0.f, 0.f};
      #pragma unroll
      for (int kb = 0; kb < 2; ++kb) {
        short8 a = *(const short8*)&Ai[w * 16 + m][kb * 32 + quad * 8];
        short8 bb = *(const short8*)&Xj[nt * 16 + m][kb * 32 + quad * 8];
        acc = __builtin_amdgcn_mfma_f32_16x16x32_bf16(a, bb, acc, 0, 0, 0);
      }
      int j = j0 + nt * 16 + m;
      float nj = nrm[((size_t)b * NUM + j) * HEADS + h];
      #pragma unroll
      for (int r = 0; r < 4; ++r) {
        float aval = fmaxf(acc[r] / fmaxf(ni[r] * nj, 1e-8f), 0.f);
        ins4(aval, j, tv[r], tj[r]);
      }
    }
  }
  __syncthreads();
  #pragma unroll
  for (int r = 0; r < 4; ++r)
    #pragma unroll
    for (int q = 0; q < 4; ++q) {
      cV[w * 16 + quad * 4 + r][m * 4 + q] = tv[r][q];
      cI[w * 16 + quad * 4 + r][m * 4 + q] = tj[r][q];
    }
  __syncthreads();
  if (tid < 64) {
    float fv[4] = {-1.f, -1.f, -1.f, -1.f};
    int fi[4] = {0x7fffffff, 0x7fffffff, 0x7fffffff, 0x7fffffff};
    for (int q = 0; q < 64; ++q) ins4(cV[tid][q], cI[tid][q], fv, fi);
    #pragma unroll
    for (int q = 0; q < 4; ++q) vec[fi[q]] = 1u;  // benign race, all write 1
  }
}

// ---------------- masked attention apply (bf16 MFMA scores + PV) ----------------
// w_ij = (relu(cos_ij) * mroi_ij * sm_j * vec_j + (i==j && sm_i==0)) * 0.25
// om[i,c] = sum_j w_ij * conv[j,c]; out = om (+ addsrc)
__global__ __launch_bounds__(256) void apply_kernel(
    const float* __restrict__ x, const float* __restrict__ conv,
    const float* __restrict__ addsrc, float* __restrict__ out,
    const float* __restrict__ nrm, const unsigned* __restrict__ vec,
    const int* __restrict__ mroi, const int* __restrict__ smask) {
  __shared__ __align__(16) bf Ai[64][LDK];
  __shared__ __align__(16) bf Xj[64][LDK];   // x tile for scores, then conv^T tile for PV
  __shared__ __align__(16) bf Ws[64][LDK];
  const int b = blockIdx.z, h = blockIdx.y, i0 = blockIdx.x * 64;
  const int tid = threadIdx.x, lane = tid & 63, w = tid >> 6;
  const int m = lane & 15, quad = lane >> 4;

  stage_tile(x, (size_t)b * NUM + i0, h * DK, CH, Ai, tid);
  float ni[4]; int smi[4];
  #pragma unroll
  for (int r = 0; r < 4; ++r) {
    int row = i0 + w * 16 + quad * 4 + r;
    ni[r] = nrm[((size_t)b * NUM + row) * HEADS + h];
    smi[r] = smask[b * NUM + row];
  }
  f32x4 om[4] = {{0.f,0.f,0.f,0.f},{0.f,0.f,0.f,0.f},{0.f,0.f,0.f,0.f},{0.f,0.f,0.f,0.f}};

  for (int j0 = 0; j0 < NUM; j0 += 64) {
    __syncthreads();
    stage_tile(x, (size_t)b * NUM + j0, h * DK, CH, Xj, tid);
    __syncthreads();
    // scores -> masked weights -> Ws (own wave's rows only)
    #pragma unroll
    for (int nt = 0; nt < 4; ++nt) {
      f32x4 acc = {0.f, 0.f, 0.f, 0.f};
      #pragma unroll
      for (int kb = 0; kb < 2; ++kb) {
        short8 a = *(const short8*)&Ai[w * 16 + m][kb * 32 + quad * 8];
        short8 bb = *(const short8*)&Xj[nt * 16 + m][kb * 32 + quad * 8];
        acc = __builtin_amdgcn_mfma_f32_16x16x32_bf16(a, bb, acc, 0, 0, 0);
      }
      int j = j0 + nt * 16 + m;
      float nj = nrm[((size_t)b * NUM + j) * HEADS + h];
      bool colok = (smask[b * NUM + j] != 0) && (vec[j] != 0u);
      #pragma unroll
      for (int r = 0; r < 4; ++r) {
        int i = i0 + w * 16 + quad * 4 + r;
        float aval = fmaxf(acc[r] / fmaxf(ni[r] * nj, 1e-8f), 0.f);
        bool cond = colok && (mroi[((size_t)b * NUM + i) * NUM + j] != 0);
        float wgt = cond ? aval * 0.25f : 0.f;
        if (i == j && smi[r] == 0) wgt += 0.25f;
        Ws[w * 16 + quad * 4 + r][nt * 16 + m] = tobf(wgt);
      }
    }
    __syncthreads();  // scores done by all waves; Xj dead -> stage conv^T into it
    {
      int jr = tid >> 4, c4 = tid & 15;
      #pragma unroll
      for (int it = 0; it < 4; ++it) {
        int j = jr + it * 16;
        const float4 v = *(const float4*)&conv[((size_t)b * NUM + j0 + j) * CH + h * DK + c4 * 4];
        Xj[c4 * 4 + 0][j] = tobf(v.x);
        Xj[c4 * 4 + 1][j] = tobf(v.y);
        Xj[c4 * 4 + 2][j] = tobf(v.z);
        Xj[c4 * 4 + 3][j] = tobf(v.w);
      }
    }
    __syncthreads();
    // PV: om[i][c] += sum_j Ws[i][j] * convT[c][j]
    #pragma unroll
    for (int kb = 0; kb < 2; ++kb) {
      short8 a = *(const short8*)&Ws[w * 16 + m][kb * 32 + quad * 8];
      #pragma unroll
      for (int ct = 0; ct < 4; ++ct) {
        short8 bb = *(const short8*)&Xj[ct * 16 + m][kb * 32 + quad * 8];
        om[ct] = __builtin_amdgcn_mfma_f32_16x16x32_bf16(a, bb, om[ct], 0, 0, 0);
      }
    }
  }
  #pragma unroll
  for (int ct = 0; ct < 4; ++ct)
    #pragma unroll
    for (int r = 0; r < 4; ++r) {
      size_t idx = ((size_t)b * NUM + i0 + w * 16 + quad * 4 + r) * CH + h * DK + ct * 16 + m;
      float v = om[ct][r];
      if (addsrc) v += addsrc[idx];
      out[idx] = v;
    }
}

// ---------------- LayerNorm + final outputs (in-place on d_out regions) ----------------
__global__ __launch_bounds__(256) void final_kernel(
    float* __restrict__ ybnf, float* __restrict__ out0,
    const float* __restrict__ lnw, const float* __restrict__ lnb) {
  __shared__ float r1[4];
  __shared__ float r2[4];
  int bn = blockIdx.x;
  int c = threadIdx.x;
  size_t idx = (size_t)bn * CH + c;
  float y = ybnf[idx];
  float x2v = out0[idx];
  float s = y;
  #pragma unroll
  for (int off = 32; off; off >>= 1) s += __shfl_down(s, off, 64);
  int wave = c >> 6, lane = c & 63;
  if (lane == 0) r1[wave] = s;
  __syncthreads();
  float mu = (r1[0] + r1[1] + r1[2] + r1[3]) * (1.f / 256.f);
  float d = y - mu;
  float s2 = d * d;
  #pragma unroll
  for (int off = 32; off; off >>= 1) s2 += __shfl_down(s2, off, 64);
  if (lane == 0) r2[wave] = s2;
  __syncthreads();
  float var = (r2[0] + r2[1] + r2[2] + r2[3]) * (1.f / 256.f);
  float nf = d * rsqrtf(var + 1e-6f) * lnw[c] + lnb[c];
  ybnf[idx] = nf;
  out0[idx] = x2v + nf;
}

extern "C" void kernel_launch(void* const* d_in, const int* in_sizes, int n_in,
                              void* d_out, int out_size, void* d_ws, size_t ws_size,
                              hipStream_t stream) {
  const float* input = (const float*)d_in[0];
  const int* mroi = (const int*)d_in[1];
  const int* smask = (const int*)d_in[2];
  const float* gt_feat = (const float*)d_in[3];
  const float* w1 = (const float*)d_in[4];
  const float* b1 = (const float*)d_in[5];
  const float* w2 = (const float*)d_in[6];
  const float* b2 = (const float*)d_in[7];
  const float* gt_w = (const float*)d_in[8];
  const float* gt_b = (const float*)d_in[9];
  const float* lnw = (const float*)d_in[10];
  const float* lnb = (const float*)d_in[11];

  const size_t SEG = (size_t)B_ * NUM * CH;  // 1048576 elements
  float* out0 = (float*)d_out;     // finally: out2^T + node_feat ; interim: X2 (conv2)
  float* gts = out0 + SEG;         // gts output (final from the start)
  float* nfreg = out0 + 2 * SEG;   // finally: node_feat ; interim: X1 then Yb

  float* F1 = (float*)d_ws;        // 4 MB
  float* NRM = F1 + SEG;           // 64 KB
  unsigned* VEC1 = (unsigned*)(NRM + (size_t)B_ * NUM * HEADS);
  unsigned* VEC2 = VEC1 + NUM;

  float* X1 = nfreg;  // conv1 output lives in node_feat region until apply1 consumes it
  float* X2 = out0;   // conv2 output lives in out0 region until final_kernel
  float* Yb = nfreg;  // o2m lives in node_feat region until final_kernel (X1 dead)

  zero_vec_kernel<<<4, 256, 0, stream>>>(VEC1, VEC2);
  gts_kernel<<<dim3(64, 4), 256, 0, stream>>>(gt_feat, gt_w, gt_b, gts);

  // stage 1
  conv_kernel<<<dim3(64, 4), 256, 0, stream>>>(input, w1, b1, X1);
  norms_kernel<<<4096, 256, 0, stream>>>(input, NRM);
  topk_kernel<<<dim3(16, HEADS, B_), 256, 0, stream>>>(input, NRM, VEC1);
  apply_kernel<<<dim3(16, HEADS, B_), 256, 0, stream>>>(
      input, X1, X1, F1, NRM, VEC1, mroi, smask);

  // stage 2
  conv_kernel<<<dim3(64, 4), 256, 0, stream>>>(F1, w2, b2, X2);
  norms_kernel<<<4096, 256, 0, stream>>>(F1, NRM);
  topk_kernel<<<dim3(16, HEADS, B_), 256, 0, stream>>>(F1, NRM, VEC2);
  apply_kernel<<<dim3(16, HEADS, B_), 256, 0, stream>>>(
      F1, X2, nullptr, Yb, NRM, VEC2, mroi, smask);

  final_kernel<<<4096, 256, 0, stream>>>(Yb, X2, lnw, lnb);
}

// Round 5
// 355.968 us; speedup vs baseline: 2.1396x; 1.4082x over previous
//
#include <hip/hip_runtime.h>
#include <hip/hip_bf16.h>

#define B_    4
#define NUM   1024
#define CH    256
#define HEADS 4
#define DK    64
#define LDK   72   // padded LDS row stride in bf16 elements (2-way bank alias = free)
#define NJC   4    // j-chunks per (b,h,i-tile)

typedef __hip_bfloat16 bf;
typedef __attribute__((ext_vector_type(8))) short short8;
typedef __attribute__((ext_vector_type(4))) float f32x4;

__device__ inline bf tobf(float v) { return __float2bfloat16(v); }

// ---------------- zero the topk union masks ----------------
__global__ void zero_vec_kernel(unsigned* v1, unsigned* v2) {
  int i = blockIdx.x * blockDim.x + threadIdx.x;
  if (i < NUM) { v1[i] = 0u; v2[i] = 0u; }
}

// ---------------- zero a SEG-sized fp32 buffer (float4 stores) ----------------
__global__ __launch_bounds__(256) void zero_buf_kernel(float* __restrict__ p) {
  size_t i = ((size_t)blockIdx.x * 256 + threadIdx.x) * 4;
  *(float4*)&p[i] = make_float4(0.f, 0.f, 0.f, 0.f);
}

// stage a 64x64 fp32 global tile -> bf16 LDS tile [64][LDK]
__device__ inline void stage_tile(const float* __restrict__ src, size_t row0,
                                  int col0, int rowstride, bf (*dst)[LDK], int tid) {
  int r = tid >> 4, c4 = (tid & 15) * 4;
  #pragma unroll
  for (int it = 0; it < 4; ++it) {
    int row = r + it * 16;
    const float4 v = *(const float4*)&src[(row0 + row) * (size_t)rowstride + col0 + c4];
    union { bf h4[4]; short4 s4; } u;
    u.h4[0] = tobf(v.x); u.h4[1] = tobf(v.y); u.h4[2] = tobf(v.z); u.h4[3] = tobf(v.w);
    *(short4*)&dst[row][c4] = u.s4;
  }
}

// ---------------- gts = relu(gt_feat @ gt_w^T + gt_b), bf16 MFMA ----------------
__global__ __launch_bounds__(256) void gts_kernel(
    const float* __restrict__ gf, const float* __restrict__ gw,
    const float* __restrict__ gb, float* __restrict__ out) {
  __shared__ __align__(16) bf As[64][LDK];
  __shared__ __align__(16) bf Bs[64][LDK];
  const int m0 = blockIdx.x * 64, n0 = blockIdx.y * 64;
  const int tid = threadIdx.x, lane = tid & 63, w = tid >> 6;
  const int m = lane & 15, quad = lane >> 4;
  f32x4 acc[4] = {{0.f,0.f,0.f,0.f},{0.f,0.f,0.f,0.f},{0.f,0.f,0.f,0.f},{0.f,0.f,0.f,0.f}};
  for (int k0 = 0; k0 < 256; k0 += 64) {
    __syncthreads();
    stage_tile(gf, m0, k0, 256, As, tid);
    stage_tile(gw, n0, k0, 256, Bs, tid);
    __syncthreads();
    #pragma unroll
    for (int kb = 0; kb < 2; ++kb) {
      short8 a = *(const short8*)&As[w * 16 + m][kb * 32 + quad * 8];
      #pragma unroll
      for (int nt = 0; nt < 4; ++nt) {
        short8 bb = *(const short8*)&Bs[nt * 16 + m][kb * 32 + quad * 8];
        acc[nt] = __builtin_amdgcn_mfma_f32_16x16x32_bf16(a, bb, acc[nt], 0, 0, 0);
      }
    }
  }
  #pragma unroll
  for (int nt = 0; nt < 4; ++nt)
    #pragma unroll
    for (int r = 0; r < 4; ++r) {
      int row = m0 + w * 16 + quad * 4 + r, col = n0 + nt * 16 + m;
      out[(size_t)row * 256 + col] = fmaxf(acc[nt][r] + gb[col], 0.f);
    }
}

// ---------------- grouped 1x1 conv + relu (fp32), optional dual destination ----------------
__global__ __launch_bounds__(256) void conv_kernel(
    const float* __restrict__ x, const float* __restrict__ w,
    const float* __restrict__ bias, float* __restrict__ out,
    float* __restrict__ out2) {
  __shared__ float Xs[64][65];
  __shared__ float Wsm[64][65];
  const int m0 = blockIdx.x * 64, g = blockIdx.y;
  const int tid = threadIdx.x, tx = tid & 15, ty = tid >> 4;
  #pragma unroll
  for (int l = 0; l < 16; ++l) {
    int idx = tid + l * 256; int r = idx >> 6, c = idx & 63;
    Xs[r][c] = x[(size_t)(m0 + r) * CH + g * DK + c];
    Wsm[r][c] = w[g * DK * DK + r * DK + c];
  }
  __syncthreads();
  float acc[4][4] = {};
  #pragma unroll 8
  for (int k = 0; k < DK; ++k) {
    float av[4], bv[4];
    #pragma unroll
    for (int i = 0; i < 4; ++i) av[i] = Xs[ty * 4 + i][k];
    #pragma unroll
    for (int j = 0; j < 4; ++j) bv[j] = Wsm[tx * 4 + j][k];
    #pragma unroll
    for (int i = 0; i < 4; ++i)
      #pragma unroll
      for (int j = 0; j < 4; ++j) acc[i][j] += av[i] * bv[j];
  }
  #pragma unroll
  for (int i = 0; i < 4; ++i)
    #pragma unroll
    for (int j = 0; j < 4; ++j) {
      int o = g * DK + tx * 4 + j;
      size_t idx = (size_t)(m0 + ty * 4 + i) * CH + o;
      float v = fmaxf(acc[i][j] + bias[o], 0.f);
      out[idx] = v;
      if (out2) out2[idx] = v;
    }
}

// ---------------- per-node per-head L2 norms ----------------
__global__ void norms_kernel(const float* __restrict__ x, float* __restrict__ nrm) {
  int bn = blockIdx.x;
  int t = threadIdx.x;
  float v = x[(size_t)bn * CH + t];
  float s = v * v;
  #pragma unroll
  for (int off = 32; off; off >>= 1) s += __shfl_down(s, off, 64);
  if ((t & 63) == 0) nrm[bn * HEADS + (t >> 6)] = sqrtf(s);
}

// top-4 insert, jax-stable tie-break (higher value first; equal value -> lower index)
__device__ inline void ins4(float v, int id, float tv[4], int tj[4]) {
  if (v < tv[3] || (v == tv[3] && id > tj[3])) return;
  tv[3] = v; tj[3] = id;
  #pragma unroll
  for (int k = 3; k > 0; --k) {
    bool sw = (tv[k] > tv[k - 1]) || (tv[k] == tv[k - 1] && tj[k] < tj[k - 1]);
    if (sw) {
      float fv = tv[k]; tv[k] = tv[k - 1]; tv[k - 1] = fv;
      int ti = tj[k]; tj[k] = tj[k - 1]; tj[k - 1] = ti;
    }
  }
}

// ---------------- per-row top-4 within a 256-col j-chunk (bf16 MFMA) ----------------
// candV/candI layout: ((((b*H+h)*16+it)*NJC+jc)*64 + row_local)*4 + q
__global__ __launch_bounds__(256) void topk_part_kernel(
    const float* __restrict__ x, const float* __restrict__ nrm,
    float* __restrict__ candV, int* __restrict__ candI) {
  __shared__ __align__(16) bf Ai[64][LDK];
  __shared__ __align__(16) bf Xj[64][LDK];
  __shared__ float cV[64][64];
  __shared__ int cI[64][64];
  const int b = blockIdx.z, h = blockIdx.y;
  const int it = blockIdx.x >> 2, jc = blockIdx.x & 3;
  const int i0 = it * 64;
  const int tid = threadIdx.x, lane = tid & 63, w = tid >> 6;
  const int m = lane & 15, quad = lane >> 4;

  stage_tile(x, (size_t)b * NUM + i0, h * DK, CH, Ai, tid);
  float ni[4];
  #pragma unroll
  for (int r = 0; r < 4; ++r)
    ni[r] = nrm[((size_t)b * NUM + i0 + w * 16 + quad * 4 + r) * HEADS + h];

  float tv[4][4]; int tj[4][4];
  #pragma unroll
  for (int r = 0; r < 4; ++r)
    #pragma unroll
    for (int q = 0; q < 4; ++q) { tv[r][q] = -1.f; tj[r][q] = 0x7fffffff; }

  for (int jt = 0; jt < 4; ++jt) {
    int j0 = jc * 256 + jt * 64;
    __syncthreads();
    stage_tile(x, (size_t)b * NUM + j0, h * DK, CH, Xj, tid);
    __syncthreads();
    #pragma unroll
    for (int nt = 0; nt < 4; ++nt) {
      f32x4 acc = {0.f, 0.f, 0.f, 0.f};
      #pragma unroll
      for (int kb = 0; kb < 2; ++kb) {
        short8 a = *(const short8*)&Ai[w * 16 + m][kb * 32 + quad * 8];
        short8 bb = *(const short8*)&Xj[nt * 16 + m][kb * 32 + quad * 8];
        acc = __builtin_amdgcn_mfma_f32_16x16x32_bf16(a, bb, acc, 0, 0, 0);
      }
      int j = j0 + nt * 16 + m;
      float nj = nrm[((size_t)b * NUM + j) * HEADS + h];
      #pragma unroll
      for (int r = 0; r < 4; ++r) {
        float aval = fmaxf(acc[r] / fmaxf(ni[r] * nj, 1e-8f), 0.f);
        ins4(aval, j, tv[r], tj[r]);
      }
    }
  }
  __syncthreads();
  #pragma unroll
  for (int r = 0; r < 4; ++r)
    #pragma unroll
    for (int q = 0; q < 4; ++q) {
      cV[w * 16 + quad * 4 + r][m * 4 + q] = tv[r][q];
      cI[w * 16 + quad * 4 + r][m * 4 + q] = tj[r][q];
    }
  __syncthreads();
  if (tid < 64) {
    float fv[4] = {-1.f, -1.f, -1.f, -1.f};
    int fi[4] = {0x7fffffff, 0x7fffffff, 0x7fffffff, 0x7fffffff};
    for (int q = 0; q < 64; ++q) ins4(cV[tid][q], cI[tid][q], fv, fi);
    size_t base = (size_t)((((b * HEADS + h) * 16 + it) * NJC + jc) * 64 + tid) * 4;
    #pragma unroll
    for (int q = 0; q < 4; ++q) { candV[base + q] = fv[q]; candI[base + q] = fi[q]; }
  }
}

// ---------------- merge NJC chunk candidates per row -> union into vec ----------------
// one thread per (b,h,it,row_local): 16384 threads
__global__ __launch_bounds__(256) void topk_merge_kernel(
    const float* __restrict__ candV, const int* __restrict__ candI,
    unsigned* __restrict__ vec) {
  int t = blockIdx.x * 256 + threadIdx.x;   // t = bhit*64 + rl
  int bhit = t >> 6, rl = t & 63;
  float fv[4] = {-1.f, -1.f, -1.f, -1.f};
  int fi[4] = {0x7fffffff, 0x7fffffff, 0x7fffffff, 0x7fffffff};
  #pragma unroll
  for (int jc = 0; jc < NJC; ++jc) {
    size_t base = (size_t)(((bhit) * NJC + jc) * 64 + rl) * 4;
    #pragma unroll
    for (int q = 0; q < 4; ++q) ins4(candV[base + q], candI[base + q], fv, fi);
  }
  #pragma unroll
  for (int q = 0; q < 4; ++q) vec[fi[q]] = 1u;  // benign race, all write 1
}

// ---------------- masked attention apply (bf16 MFMA scores + PV), j-chunked ----------------
// w_ij = (relu(cos_ij) * mroi_ij * sm_j * vec_j + (i==j && sm_i==0)) * 0.25
// atomicAdd partial om into out (out pre-initialized with addend or zero)
__global__ __launch_bounds__(256) void apply_kernel(
    const float* __restrict__ x, const float* __restrict__ conv,
    float* __restrict__ out,
    const float* __restrict__ nrm, const unsigned* __restrict__ vec,
    const int* __restrict__ mroi, const int* __restrict__ smask) {
  __shared__ __align__(16) bf Ai[64][LDK];
  __shared__ __align__(16) bf Xj[64][LDK];   // x tile for scores, then conv^T tile for PV
  __shared__ __align__(16) bf Ws[64][LDK];
  const int b = blockIdx.z, h = blockIdx.y;
  const int it = blockIdx.x >> 2, jc = blockIdx.x & 3;
  const int i0 = it * 64;
  const int tid = threadIdx.x, lane = tid & 63, w = tid >> 6;
  const int m = lane & 15, quad = lane >> 4;

  stage_tile(x, (size_t)b * NUM + i0, h * DK, CH, Ai, tid);
  float ni[4]; int smi[4];
  #pragma unroll
  for (int r = 0; r < 4; ++r) {
    int row = i0 + w * 16 + quad * 4 + r;
    ni[r] = nrm[((size_t)b * NUM + row) * HEADS + h];
    smi[r] = smask[b * NUM + row];
  }
  f32x4 om[4] = {{0.f,0.f,0.f,0.f},{0.f,0.f,0.f,0.f},{0.f,0.f,0.f,0.f},{0.f,0.f,0.f,0.f}};

  for (int jt = 0; jt < 4; ++jt) {
    int j0 = jc * 256 + jt * 64;
    __syncthreads();
    stage_tile(x, (size_t)b * NUM + j0, h * DK, CH, Xj, tid);
    __syncthreads();
    // scores -> masked weights -> Ws (own wave's rows only)
    #pragma unroll
    for (int nt = 0; nt < 4; ++nt) {
      f32x4 acc = {0.f, 0.f, 0.f, 0.f};
      #pragma unroll
      for (int kb = 0; kb < 2; ++kb) {
        short8 a = *(const short8*)&Ai[w * 16 + m][kb * 32 + quad * 8];
        short8 bb = *(const short8*)&Xj[nt * 16 + m][kb * 32 + quad * 8];
        acc = __builtin_amdgcn_mfma_f32_16x16x32_bf16(a, bb, acc, 0, 0, 0);
      }
      int j = j0 + nt * 16 + m;
      float nj = nrm[((size_t)b * NUM + j) * HEADS + h];
      bool colok = (smask[b * NUM + j] != 0) && (vec[j] != 0u);
      #pragma unroll
      for (int r = 0; r < 4; ++r) {
        int i = i0 + w * 16 + quad * 4 + r;
        float aval = fmaxf(acc[r] / fmaxf(ni[r] * nj, 1e-8f), 0.f);
        bool cond = colok && (mroi[((size_t)b * NUM + i) * NUM + j] != 0);
        float wgt = cond ? aval * 0.25f : 0.f;
        if (i == j && smi[r] == 0) wgt += 0.25f;
        Ws[w * 16 + quad * 4 + r][nt * 16 + m] = tobf(wgt);
      }
    }
    __syncthreads();  // scores done by all waves; Xj dead -> stage conv^T into it
    {
      int jr = tid >> 4, c4 = tid & 15;
      #pragma unroll
      for (int itt = 0; itt < 4; ++itt) {
        int j = jr + itt * 16;
        const float4 v = *(const float4*)&conv[((size_t)b * NUM + j0 + j) * CH + h * DK + c4 * 4];
        Xj[c4 * 4 + 0][j] = tobf(v.x);
        Xj[c4 * 4 + 1][j] = tobf(v.y);
        Xj[c4 * 4 + 2][j] = tobf(v.z);
        Xj[c4 * 4 + 3][j] = tobf(v.w);
      }
    }
    __syncthreads();
    // PV: om[i][c] += sum_j Ws[i][j] * convT[c][j]
    #pragma unroll
    for (int kb = 0; kb < 2; ++kb) {
      short8 a = *(const short8*)&Ws[w * 16 + m][kb * 32 + quad * 8];
      #pragma unroll
      for (int ct = 0; ct < 4; ++ct) {
        short8 bb = *(const short8*)&Xj[ct * 16 + m][kb * 32 + quad * 8];
        om[ct] = __builtin_amdgcn_mfma_f32_16x16x32_bf16(a, bb, om[ct], 0, 0, 0);
      }
    }
  }
  #pragma unroll
  for (int ct = 0; ct < 4; ++ct)
    #pragma unroll
    for (int r = 0; r < 4; ++r) {
      size_t idx = ((size_t)b * NUM + i0 + w * 16 + quad * 4 + r) * CH + h * DK + ct * 16 + m;
      atomicAdd(&out[idx], om[ct][r]);
    }
}

// ---------------- LayerNorm + final outputs (in-place on d_out regions) ----------------
__global__ __launch_bounds__(256) void final_kernel(
    float* __restrict__ ybnf, float* __restrict__ out0,
    const float* __restrict__ lnw, const float* __restrict__ lnb) {
  __shared__ float r1[4];
  __shared__ float r2[4];
  int bn = blockIdx.x;
  int c = threadIdx.x;
  size_t idx = (size_t)bn * CH + c;
  float y = ybnf[idx];
  float x2v = out0[idx];
  float s = y;
  #pragma unroll
  for (int off = 32; off; off >>= 1) s += __shfl_down(s, off, 64);
  int wave = c >> 6, lane = c & 63;
  if (lane == 0) r1[wave] = s;
  __syncthreads();
  float mu = (r1[0] + r1[1] + r1[2] + r1[3]) * (1.f / 256.f);
  float d = y - mu;
  float s2 = d * d;
  #pragma unroll
  for (int off = 32; off; off >>= 1) s2 += __shfl_down(s2, off, 64);
  if (lane == 0) r2[wave] = s2;
  __syncthreads();
  float var = (r2[0] + r2[1] + r2[2] + r2[3]) * (1.f / 256.f);
  float nf = d * rsqrtf(var + 1e-6f) * lnw[c] + lnb[c];
  ybnf[idx] = nf;
  out0[idx] = x2v + nf;
}

extern "C" void kernel_launch(void* const* d_in, const int* in_sizes, int n_in,
                              void* d_out, int out_size, void* d_ws, size_t ws_size,
                              hipStream_t stream) {
  const float* input = (const float*)d_in[0];
  const int* mroi = (const int*)d_in[1];
  const int* smask = (const int*)d_in[2];
  const float* gt_feat = (const float*)d_in[3];
  const float* w1 = (const float*)d_in[4];
  const float* b1 = (const float*)d_in[5];
  const float* w2 = (const float*)d_in[6];
  const float* b2 = (const float*)d_in[7];
  const float* gt_w = (const float*)d_in[8];
  const float* gt_b = (const float*)d_in[9];
  const float* lnw = (const float*)d_in[10];
  const float* lnb = (const float*)d_in[11];

  const size_t SEG = (size_t)B_ * NUM * CH;  // 1048576 elements
  float* out0 = (float*)d_out;     // finally: out2^T + node_feat ; interim: X2 (conv2)
  float* gts = out0 + SEG;         // gts output (final from the start)
  float* nfreg = out0 + 2 * SEG;   // finally: node_feat ; interim: X1 then Yb

  // ws: F1 4MB | NRM 64KB | VEC 8KB | candV 1MB | candI 1MB  ~= 6.4 MB
  float* F1 = (float*)d_ws;
  float* NRM = F1 + SEG;
  unsigned* VEC1 = (unsigned*)(NRM + (size_t)B_ * NUM * HEADS);
  unsigned* VEC2 = VEC1 + NUM;
  float* candV = (float*)(VEC2 + NUM);
  int* candI = (int*)(candV + (size_t)B_ * HEADS * 16 * NJC * 64 * 4);

  float* X1 = nfreg;  // conv1 output (also pre-seeded into F1 as apply1's addend)
  float* X2 = out0;   // conv2 output lives in out0 region until final_kernel
  float* Yb = nfreg;  // o2m accumulator (zero-seeded after X1 dies)

  zero_vec_kernel<<<4, 256, 0, stream>>>(VEC1, VEC2);
  gts_kernel<<<dim3(64, 4), 256, 0, stream>>>(gt_feat, gt_w, gt_b, gts);

  // stage 1
  conv_kernel<<<dim3(64, 4), 256, 0, stream>>>(input, w1, b1, X1, F1);  // F1 = X1 (addend seed)
  norms_kernel<<<4096, 256, 0, stream>>>(input, NRM);
  topk_part_kernel<<<dim3(64, HEADS, B_), 256, 0, stream>>>(input, NRM, candV, candI);
  topk_merge_kernel<<<64, 256, 0, stream>>>(candV, candI, VEC1);
  apply_kernel<<<dim3(64, HEADS, B_), 256, 0, stream>>>(
      input, X1, F1, NRM, VEC1, mroi, smask);

  // stage 2
  conv_kernel<<<dim3(64, 4), 256, 0, stream>>>(F1, w2, b2, X2, nullptr);
  zero_buf_kernel<<<SEG / 1024, 256, 0, stream>>>(Yb);  // X1 dead now; Yb = 0 seed
  norms_kernel<<<4096, 256, 0, stream>>>(F1, NRM);
  topk_part_kernel<<<dim3(64, HEADS, B_), 256, 0, stream>>>(F1, NRM, candV, candI);
  topk_merge_kernel<<<64, 256, 0, stream>>>(candV, candI, VEC2);
  apply_kernel<<<dim3(64, HEADS, B_), 256, 0, stream>>>(
      F1, X2, Yb, NRM, VEC2, mroi, smask);

  final_kernel<<<4096, 256, 0, stream>>>(Yb, X2, lnw, lnb);
}

// Round 6
// 329.967 us; speedup vs baseline: 2.3082x; 1.0788x over previous
//
#include <hip/hip_runtime.h>
#include <hip/hip_bf16.h>

#define B_    4
#define NUM   1024
#define CH    256
#define HEADS 4
#define DK    64
#define LDK   72   // padded LDS row stride in bf16 elements (2-way bank alias = free)
#define NJC   4    // j-chunks per (b,h,i-tile)

typedef __hip_bfloat16 bf;
typedef __attribute__((ext_vector_type(8))) short short8;
typedef __attribute__((ext_vector_type(4))) float f32x4;

__device__ inline bf tobf(float v) { return __float2bfloat16(v); }

// ---------------- zero the topk union masks ----------------
__global__ void zero_vec_kernel(unsigned* v1, unsigned* v2) {
  int i = blockIdx.x * blockDim.x + threadIdx.x;
  if (i < NUM) { v1[i] = 0u; v2[i] = 0u; }
}

// ---------------- zero a SEG-sized fp32 buffer (float4 stores) ----------------
__global__ __launch_bounds__(256) void zero_buf_kernel(float* __restrict__ p) {
  size_t i = ((size_t)blockIdx.x * 256 + threadIdx.x) * 4;
  *(float4*)&p[i] = make_float4(0.f, 0.f, 0.f, 0.f);
}

// stage a 64x64 fp32 global tile -> bf16 LDS tile [64][LDK]
__device__ inline void stage_tile(const float* __restrict__ src, size_t row0,
                                  int col0, int rowstride, bf (*dst)[LDK], int tid) {
  int r = tid >> 4, c4 = (tid & 15) * 4;
  #pragma unroll
  for (int it = 0; it < 4; ++it) {
    int row = r + it * 16;
    const float4 v = *(const float4*)&src[(row0 + row) * (size_t)rowstride + col0 + c4];
    union { bf h4[4]; short4 s4; } u;
    u.h4[0] = tobf(v.x); u.h4[1] = tobf(v.y); u.h4[2] = tobf(v.z); u.h4[3] = tobf(v.w);
    *(short4*)&dst[row][c4] = u.s4;
  }
}

// load this lane's A-fragments (2 k-blocks) straight from global into registers
__device__ inline void load_afrag(const float* __restrict__ arow, int quad, short8 af[2]) {
  #pragma unroll
  for (int kb = 0; kb < 2; ++kb) {
    const float4 v0 = *(const float4*)&arow[kb * 32 + quad * 8];
    const float4 v1 = *(const float4*)&arow[kb * 32 + quad * 8 + 4];
    union { bf hh[8]; short8 s; } u;
    u.hh[0] = tobf(v0.x); u.hh[1] = tobf(v0.y); u.hh[2] = tobf(v0.z); u.hh[3] = tobf(v0.w);
    u.hh[4] = tobf(v1.x); u.hh[5] = tobf(v1.y); u.hh[6] = tobf(v1.z); u.hh[7] = tobf(v1.w);
    af[kb] = u.s;
  }
}

// ---------------- gts = relu(gt_feat @ gt_w^T + gt_b), bf16 MFMA ----------------
__global__ __launch_bounds__(256) void gts_kernel(
    const float* __restrict__ gf, const float* __restrict__ gw,
    const float* __restrict__ gb, float* __restrict__ out) {
  __shared__ __align__(16) bf As[64][LDK];
  __shared__ __align__(16) bf Bs[64][LDK];
  const int m0 = blockIdx.x * 64, n0 = blockIdx.y * 64;
  const int tid = threadIdx.x, lane = tid & 63, w = tid >> 6;
  const int m = lane & 15, quad = lane >> 4;
  f32x4 acc[4] = {{0.f,0.f,0.f,0.f},{0.f,0.f,0.f,0.f},{0.f,0.f,0.f,0.f},{0.f,0.f,0.f,0.f}};
  for (int k0 = 0; k0 < 256; k0 += 64) {
    __syncthreads();
    stage_tile(gf, m0, k0, 256, As, tid);
    stage_tile(gw, n0, k0, 256, Bs, tid);
    __syncthreads();
    #pragma unroll
    for (int kb = 0; kb < 2; ++kb) {
      short8 a = *(const short8*)&As[w * 16 + m][kb * 32 + quad * 8];
      #pragma unroll
      for (int nt = 0; nt < 4; ++nt) {
        short8 bb = *(const short8*)&Bs[nt * 16 + m][kb * 32 + quad * 8];
        acc[nt] = __builtin_amdgcn_mfma_f32_16x16x32_bf16(a, bb, acc[nt], 0, 0, 0);
      }
    }
  }
  #pragma unroll
  for (int nt = 0; nt < 4; ++nt)
    #pragma unroll
    for (int r = 0; r < 4; ++r) {
      int row = m0 + w * 16 + quad * 4 + r, col = n0 + nt * 16 + m;
      out[(size_t)row * 256 + col] = fmaxf(acc[nt][r] + gb[col], 0.f);
    }
}

// ---------------- grouped 1x1 conv + relu (fp32), optional dual destination ----------------
__global__ __launch_bounds__(256) void conv_kernel(
    const float* __restrict__ x, const float* __restrict__ w,
    const float* __restrict__ bias, float* __restrict__ out,
    float* __restrict__ out2) {
  __shared__ float Xs[64][65];
  __shared__ float Wsm[64][65];
  const int m0 = blockIdx.x * 64, g = blockIdx.y;
  const int tid = threadIdx.x, tx = tid & 15, ty = tid >> 4;
  #pragma unroll
  for (int l = 0; l < 16; ++l) {
    int idx = tid + l * 256; int r = idx >> 6, c = idx & 63;
    Xs[r][c] = x[(size_t)(m0 + r) * CH + g * DK + c];
    Wsm[r][c] = w[g * DK * DK + r * DK + c];
  }
  __syncthreads();
  float acc[4][4] = {};
  #pragma unroll 8
  for (int k = 0; k < DK; ++k) {
    float av[4], bv[4];
    #pragma unroll
    for (int i = 0; i < 4; ++i) av[i] = Xs[ty * 4 + i][k];
    #pragma unroll
    for (int j = 0; j < 4; ++j) bv[j] = Wsm[tx * 4 + j][k];
    #pragma unroll
    for (int i = 0; i < 4; ++i)
      #pragma unroll
      for (int j = 0; j < 4; ++j) acc[i][j] += av[i] * bv[j];
  }
  #pragma unroll
  for (int i = 0; i < 4; ++i)
    #pragma unroll
    for (int j = 0; j < 4; ++j) {
      int o = g * DK + tx * 4 + j;
      size_t idx = (size_t)(m0 + ty * 4 + i) * CH + o;
      float v = fmaxf(acc[i][j] + bias[o], 0.f);
      out[idx] = v;
      if (out2) out2[idx] = v;
    }
}

// ---------------- per-node per-head L2 norms ----------------
__global__ void norms_kernel(const float* __restrict__ x, float* __restrict__ nrm) {
  int bn = blockIdx.x;
  int t = threadIdx.x;
  float v = x[(size_t)bn * CH + t];
  float s = v * v;
  #pragma unroll
  for (int off = 32; off; off >>= 1) s += __shfl_down(s, off, 64);
  if ((t & 63) == 0) nrm[bn * HEADS + (t >> 6)] = sqrtf(s);
}

// top-4 insert, jax-stable tie-break (higher value first; equal value -> lower index)
__device__ inline void ins4(float v, int id, float tv[4], int tj[4]) {
  if (v < tv[3] || (v == tv[3] && id > tj[3])) return;
  tv[3] = v; tj[3] = id;
  #pragma unroll
  for (int k = 3; k > 0; --k) {
    bool sw = (tv[k] > tv[k - 1]) || (tv[k] == tv[k - 1] && tj[k] < tj[k - 1]);
    if (sw) {
      float fv = tv[k]; tv[k] = tv[k - 1]; tv[k - 1] = fv;
      int ti = tj[k]; tj[k] = tj[k - 1]; tj[k - 1] = ti;
    }
  }
}

// ---------------- per-row top-4 within a 256-col j-chunk (bf16 MFMA) ----------------
// Ranking uses v = relu(dot * (1/nj)) -- same order & same zero-ties as
// relu(dot/(ni*nj)) since ni>0 is constant per row. candV/candI layout:
// ((((b*H+h)*16+it)*NJC+jc)*64 + row_local)*4 + q
__global__ __launch_bounds__(256) void topk_part_kernel(
    const float* __restrict__ x, const float* __restrict__ nrm,
    float* __restrict__ candV, int* __restrict__ candI) {
  __shared__ __align__(16) float cV[64][65];     // overlaid: Xj tile during j-loop
  __shared__ unsigned short cI[64][66];
  bf (*Xj)[LDK] = (bf(*)[LDK])cV;                // 9216 B <= 16640 B, safe overlay
  const int b = blockIdx.z, h = blockIdx.y;
  const int it = blockIdx.x >> 2, jc = blockIdx.x & 3;
  const int i0 = it * 64;
  const int tid = threadIdx.x, lane = tid & 63, w = tid >> 6;
  const int m = lane & 15, quad = lane >> 4;

  short8 afrag[2];
  load_afrag(&x[((size_t)b * NUM + i0 + w * 16 + m) * CH + h * DK], quad, afrag);

  float tv[4][4]; int tj[4][4];
  #pragma unroll
  for (int r = 0; r < 4; ++r)
    #pragma unroll
    for (int q = 0; q < 4; ++q) { tv[r][q] = -1.f; tj[r][q] = 0xffff; }

  for (int jt = 0; jt < 4; ++jt) {
    int j0 = jc * 256 + jt * 64;
    __syncthreads();
    stage_tile(x, (size_t)b * NUM + j0, h * DK, CH, Xj, tid);
    __syncthreads();
    #pragma unroll
    for (int nt = 0; nt < 4; ++nt) {
      f32x4 acc = {0.f, 0.f, 0.f, 0.f};
      #pragma unroll
      for (int kb = 0; kb < 2; ++kb) {
        short8 bb = *(const short8*)&Xj[nt * 16 + m][kb * 32 + quad * 8];
        acc = __builtin_amdgcn_mfma_f32_16x16x32_bf16(afrag[kb], bb, acc, 0, 0, 0);
      }
      int j = j0 + nt * 16 + m;
      float rnj = 1.0f / fmaxf(nrm[((size_t)b * NUM + j) * HEADS + h], 1e-4f);
      #pragma unroll
      for (int r = 0; r < 4; ++r) {
        float v = fmaxf(acc[r] * rnj, 0.f);
        ins4(v, j, tv[r], tj[r]);
      }
    }
  }
  __syncthreads();  // Xj dead; reuse memory as cV/cI
  #pragma unroll
  for (int r = 0; r < 4; ++r)
    #pragma unroll
    for (int q = 0; q < 4; ++q) {
      cV[w * 16 + quad * 4 + r][m * 4 + q] = tv[r][q];
      cI[w * 16 + quad * 4 + r][m * 4 + q] = (unsigned short)tj[r][q];
    }
  __syncthreads();
  if (tid < 64) {
    float fv[4] = {-1.f, -1.f, -1.f, -1.f};
    int fi[4] = {0x7fffffff, 0x7fffffff, 0x7fffffff, 0x7fffffff};
    for (int q = 0; q < 64; ++q) ins4(cV[tid][q], (int)cI[tid][q], fv, fi);
    size_t base = (size_t)((((b * HEADS + h) * 16 + it) * NJC + jc) * 64 + tid) * 4;
    #pragma unroll
    for (int q = 0; q < 4; ++q) { candV[base + q] = fv[q]; candI[base + q] = fi[q]; }
  }
}

// ---------------- merge NJC chunk candidates per row -> union into vec ----------------
__global__ __launch_bounds__(256) void topk_merge_kernel(
    const float* __restrict__ candV, const int* __restrict__ candI,
    unsigned* __restrict__ vec) {
  int t = blockIdx.x * 256 + threadIdx.x;   // t = bhit*64 + rl
  int bhit = t >> 6, rl = t & 63;
  float fv[4] = {-1.f, -1.f, -1.f, -1.f};
  int fi[4] = {0x7fffffff, 0x7fffffff, 0x7fffffff, 0x7fffffff};
  #pragma unroll
  for (int jc = 0; jc < NJC; ++jc) {
    size_t base = (size_t)(((bhit) * NJC + jc) * 64 + rl) * 4;
    #pragma unroll
    for (int q = 0; q < 4; ++q) ins4(candV[base + q], candI[base + q], fv, fi);
  }
  #pragma unroll
  for (int q = 0; q < 4; ++q) vec[fi[q]] = 1u;  // benign race, all write 1
}

// ---------------- masked attention apply (bf16 MFMA scores + PV), j-chunked ----------------
// w_ij = (relu(cos_ij) * mroi_ij * sm_j * vec_j + (i==j && sm_i==0)) * 0.25
// cos*0.25 computed as acc * rni4[r] * rnj (rcp products, no divide).
// atomicAdd partial om into out (out pre-initialized with addend or zero).
__global__ __launch_bounds__(256) void apply_kernel(
    const float* __restrict__ x, const float* __restrict__ conv,
    float* __restrict__ out,
    const float* __restrict__ nrm, const unsigned* __restrict__ vec,
    const int* __restrict__ mroi, const int* __restrict__ smask) {
  __shared__ __align__(16) bf Xj[64][LDK];   // x tile for scores, then conv^T tile for PV
  __shared__ __align__(16) bf Ws[64][LDK];
  const int b = blockIdx.z, h = blockIdx.y;
  const int it = blockIdx.x >> 2, jc = blockIdx.x & 3;
  const int i0 = it * 64;
  const int tid = threadIdx.x, lane = tid & 63, w = tid >> 6;
  const int m = lane & 15, quad = lane >> 4;

  short8 afrag[2];
  load_afrag(&x[((size_t)b * NUM + i0 + w * 16 + m) * CH + h * DK], quad, afrag);

  float rni4[4]; int smi[4];
  #pragma unroll
  for (int r = 0; r < 4; ++r) {
    int row = i0 + w * 16 + quad * 4 + r;
    rni4[r] = 0.25f / fmaxf(nrm[((size_t)b * NUM + row) * HEADS + h], 1e-4f);
    smi[r] = smask[b * NUM + row];
  }
  f32x4 om[4] = {{0.f,0.f,0.f,0.f},{0.f,0.f,0.f,0.f},{0.f,0.f,0.f,0.f},{0.f,0.f,0.f,0.f}};

  for (int jt = 0; jt < 4; ++jt) {
    int j0 = jc * 256 + jt * 64;
    __syncthreads();
    stage_tile(x, (size_t)b * NUM + j0, h * DK, CH, Xj, tid);
    __syncthreads();
    // scores -> masked weights -> Ws (own wave's rows only)
    #pragma unroll
    for (int nt = 0; nt < 4; ++nt) {
      f32x4 acc = {0.f, 0.f, 0.f, 0.f};
      #pragma unroll
      for (int kb = 0; kb < 2; ++kb) {
        short8 bb = *(const short8*)&Xj[nt * 16 + m][kb * 32 + quad * 8];
        acc = __builtin_amdgcn_mfma_f32_16x16x32_bf16(afrag[kb], bb, acc, 0, 0, 0);
      }
      int j = j0 + nt * 16 + m;
      float rnj = 1.0f / fmaxf(nrm[((size_t)b * NUM + j) * HEADS + h], 1e-4f);
      bool colok = (smask[b * NUM + j] != 0) && (vec[j] != 0u);
      #pragma unroll
      for (int r = 0; r < 4; ++r) {
        int i = i0 + w * 16 + quad * 4 + r;
        float a = fmaxf(acc[r] * rni4[r] * rnj, 0.f);   // includes *0.25
        bool cond = colok && (mroi[((size_t)b * NUM + i) * NUM + j] != 0);
        float wgt = cond ? a : 0.f;
        if (i == j && smi[r] == 0) wgt += 0.25f;
        Ws[w * 16 + quad * 4 + r][nt * 16 + m] = tobf(wgt);
      }
    }
    __syncthreads();  // scores done by all waves; Xj dead -> stage conv^T into it
    {
      int jr = tid >> 4, c4 = tid & 15;
      #pragma unroll
      for (int itt = 0; itt < 4; ++itt) {
        int j = jr + itt * 16;
        const float4 v = *(const float4*)&conv[((size_t)b * NUM + j0 + j) * CH + h * DK + c4 * 4];
        Xj[c4 * 4 + 0][j] = tobf(v.x);
        Xj[c4 * 4 + 1][j] = tobf(v.y);
        Xj[c4 * 4 + 2][j] = tobf(v.z);
        Xj[c4 * 4 + 3][j] = tobf(v.w);
      }
    }
    __syncthreads();
    // PV: om[i][c] += sum_j Ws[i][j] * convT[c][j]
    #pragma unroll
    for (int kb = 0; kb < 2; ++kb) {
      short8 a = *(const short8*)&Ws[w * 16 + m][kb * 32 + quad * 8];
      #pragma unroll
      for (int ct = 0; ct < 4; ++ct) {
        short8 bb = *(const short8*)&Xj[ct * 16 + m][kb * 32 + quad * 8];
        om[ct] = __builtin_amdgcn_mfma_f32_16x16x32_bf16(a, bb, om[ct], 0, 0, 0);
      }
    }
  }
  #pragma unroll
  for (int ct = 0; ct < 4; ++ct)
    #pragma unroll
    for (int r = 0; r < 4; ++r) {
      size_t idx = ((size_t)b * NUM + i0 + w * 16 + quad * 4 + r) * CH + h * DK + ct * 16 + m;
      atomicAdd(&out[idx], om[ct][r]);
    }
}

// ---------------- LayerNorm + final outputs (in-place on d_out regions) ----------------
__global__ __launch_bounds__(256) void final_kernel(
    float* __restrict__ ybnf, float* __restrict__ out0,
    const float* __restrict__ lnw, const float* __restrict__ lnb) {
  __shared__ float r1[4];
  __shared__ float r2[4];
  int bn = blockIdx.x;
  int c = threadIdx.x;
  size_t idx = (size_t)bn * CH + c;
  float y = ybnf[idx];
  float x2v = out0[idx];
  float s = y;
  #pragma unroll
  for (int off = 32; off; off >>= 1) s += __shfl_down(s, off, 64);
  int wave = c >> 6, lane = c & 63;
  if (lane == 0) r1[wave] = s;
  __syncthreads();
  float mu = (r1[0] + r1[1] + r1[2] + r1[3]) * (1.f / 256.f);
  float d = y - mu;
  float s2 = d * d;
  #pragma unroll
  for (int off = 32; off; off >>= 1) s2 += __shfl_down(s2, off, 64);
  if (lane == 0) r2[wave] = s2;
  __syncthreads();
  float var = (r2[0] + r2[1] + r2[2] + r2[3]) * (1.f / 256.f);
  float nf = d * rsqrtf(var + 1e-6f) * lnw[c] + lnb[c];
  ybnf[idx] = nf;
  out0[idx] = x2v + nf;
}

extern "C" void kernel_launch(void* const* d_in, const int* in_sizes, int n_in,
                              void* d_out, int out_size, void* d_ws, size_t ws_size,
                              hipStream_t stream) {
  const float* input = (const float*)d_in[0];
  const int* mroi = (const int*)d_in[1];
  const int* smask = (const int*)d_in[2];
  const float* gt_feat = (const float*)d_in[3];
  const float* w1 = (const float*)d_in[4];
  const float* b1 = (const float*)d_in[5];
  const float* w2 = (const float*)d_in[6];
  const float* b2 = (const float*)d_in[7];
  const float* gt_w = (const float*)d_in[8];
  const float* gt_b = (const float*)d_in[9];
  const float* lnw = (const float*)d_in[10];
  const float* lnb = (const float*)d_in[11];

  const size_t SEG = (size_t)B_ * NUM * CH;  // 1048576 elements
  float* out0 = (float*)d_out;     // finally: out2^T + node_feat ; interim: X2 (conv2)
  float* gts = out0 + SEG;         // gts output (final from the start)
  float* nfreg = out0 + 2 * SEG;   // finally: node_feat ; interim: X1 then Yb

  // ws: F1 4MB | NRM 64KB | VEC 8KB | candV 1MB | candI 1MB  ~= 6.4 MB
  float* F1 = (float*)d_ws;
  float* NRM = F1 + SEG;
  unsigned* VEC1 = (unsigned*)(NRM + (size_t)B_ * NUM * HEADS);
  unsigned* VEC2 = VEC1 + NUM;
  float* candV = (float*)(VEC2 + NUM);
  int* candI = (int*)(candV + (size_t)B_ * HEADS * 16 * NJC * 64 * 4);

  float* X1 = nfreg;  // conv1 output (also pre-seeded into F1 as apply1's addend)
  float* X2 = out0;   // conv2 output lives in out0 region until final_kernel
  float* Yb = nfreg;  // o2m accumulator (zero-seeded after X1 dies)

  zero_vec_kernel<<<4, 256, 0, stream>>>(VEC1, VEC2);
  gts_kernel<<<dim3(64, 4), 256, 0, stream>>>(gt_feat, gt_w, gt_b, gts);

  // stage 1
  conv_kernel<<<dim3(64, 4), 256, 0, stream>>>(input, w1, b1, X1, F1);  // F1 = X1 (addend seed)
  norms_kernel<<<4096, 256, 0, stream>>>(input, NRM);
  topk_part_kernel<<<dim3(64, HEADS, B_), 256, 0, stream>>>(input, NRM, candV, candI);
  topk_merge_kernel<<<64, 256, 0, stream>>>(candV, candI, VEC1);
  apply_kernel<<<dim3(64, HEADS, B_), 256, 0, stream>>>(
      input, X1, F1, NRM, VEC1, mroi, smask);

  // stage 2
  conv_kernel<<<dim3(64, 4), 256, 0, stream>>>(F1, w2, b2, X2, nullptr);
  zero_buf_kernel<<<SEG / 1024, 256, 0, stream>>>(Yb);  // X1 dead now; Yb = 0 seed
  norms_kernel<<<4096, 256, 0, stream>>>(F1, NRM);
  topk_part_kernel<<<dim3(64, HEADS, B_), 256, 0, stream>>>(F1, NRM, candV, candI);
  topk_merge_kernel<<<64, 256, 0, stream>>>(candV, candI, VEC2);
  apply_kernel<<<dim3(64, HEADS, B_), 256, 0, stream>>>(
      F1, X2, Yb, NRM, VEC2, mroi, smask);

  final_kernel<<<4096, 256, 0, stream>>>(Yb, X2, lnw, lnb);
}

// Round 7
// 293.276 us; speedup vs baseline: 2.5969x; 1.1251x over previous
//
#include <hip/hip_runtime.h>
#include <hip/hip_bf16.h>

#define B_    4
#define NUM   1024
#define CH    256
#define HEADS 4
#define DK    64
#define LDK   72   // padded LDS row stride in bf16 elements (2-way bank alias = free)
#define NJC   4    // j-chunks per (b,h,i-tile)

typedef __hip_bfloat16 bf;
typedef __attribute__((ext_vector_type(8))) short short8;
typedef __attribute__((ext_vector_type(4))) float f32x4;
typedef unsigned long long u64;

__device__ inline bf tobf(float v) { return __float2bfloat16(v); }

// ---------------- zero the topk union masks (float 0/1) ----------------
__global__ void zero_vec_kernel(float* v1, float* v2) {
  int i = blockIdx.x * blockDim.x + threadIdx.x;
  if (i < NUM) { v1[i] = 0.f; v2[i] = 0.f; }
}

// ---------------- pack (mroi && smask_j) into bit-words: pk[row][jw] ----------------
// one wave per row (b*NUM+i); lane l covers bit j = jw*64 + l
__global__ __launch_bounds__(256) void pack_kernel(
    const int* __restrict__ mroi, const int* __restrict__ smask,
    u64* __restrict__ pk) {
  int row = blockIdx.x * 4 + (threadIdx.x >> 6);
  int lane = threadIdx.x & 63;
  int b = row >> 10;
  const int* mr = &mroi[(size_t)row * NUM];
  const int* sm = &smask[b * NUM];
  #pragma unroll
  for (int w = 0; w < 16; ++w) {
    int j = w * 64 + lane;
    u64 word = __ballot((mr[j] != 0) && (sm[j] != 0));
    if (lane == 0) pk[(size_t)row * 16 + w] = word;
  }
}

// stage a 64x64 fp32 global tile -> bf16 LDS tile [64][LDK]
__device__ inline void stage_tile(const float* __restrict__ src, size_t row0,
                                  int col0, int rowstride, bf (*dst)[LDK], int tid) {
  int r = tid >> 4, c4 = (tid & 15) * 4;
  #pragma unroll
  for (int it = 0; it < 4; ++it) {
    int row = r + it * 16;
    const float4 v = *(const float4*)&src[(row0 + row) * (size_t)rowstride + col0 + c4];
    union { bf h4[4]; short4 s4; } u;
    u.h4[0] = tobf(v.x); u.h4[1] = tobf(v.y); u.h4[2] = tobf(v.z); u.h4[3] = tobf(v.w);
    *(short4*)&dst[row][c4] = u.s4;
  }
}

// load this lane's A-fragments (2 k-blocks) straight from global into registers
__device__ inline void load_afrag(const float* __restrict__ arow, int quad, short8 af[2]) {
  #pragma unroll
  for (int kb = 0; kb < 2; ++kb) {
    const float4 v0 = *(const float4*)&arow[kb * 32 + quad * 8];
    const float4 v1 = *(const float4*)&arow[kb * 32 + quad * 8 + 4];
    union { bf hh[8]; short8 s; } u;
    u.hh[0] = tobf(v0.x); u.hh[1] = tobf(v0.y); u.hh[2] = tobf(v0.z); u.hh[3] = tobf(v0.w);
    u.hh[4] = tobf(v1.x); u.hh[5] = tobf(v1.y); u.hh[6] = tobf(v1.z); u.hh[7] = tobf(v1.w);
    af[kb] = u.s;
  }
}

// ---------------- gts = relu(gt_feat @ gt_w^T + gt_b), bf16 MFMA ----------------
__global__ __launch_bounds__(256) void gts_kernel(
    const float* __restrict__ gf, const float* __restrict__ gw,
    const float* __restrict__ gb, float* __restrict__ out) {
  __shared__ __align__(16) bf As[64][LDK];
  __shared__ __align__(16) bf Bs[64][LDK];
  const int m0 = blockIdx.x * 64, n0 = blockIdx.y * 64;
  const int tid = threadIdx.x, lane = tid & 63, w = tid >> 6;
  const int m = lane & 15, quad = lane >> 4;
  f32x4 acc[4] = {{0.f,0.f,0.f,0.f},{0.f,0.f,0.f,0.f},{0.f,0.f,0.f,0.f},{0.f,0.f,0.f,0.f}};
  for (int k0 = 0; k0 < 256; k0 += 64) {
    __syncthreads();
    stage_tile(gf, m0, k0, 256, As, tid);
    stage_tile(gw, n0, k0, 256, Bs, tid);
    __syncthreads();
    #pragma unroll
    for (int kb = 0; kb < 2; ++kb) {
      short8 a = *(const short8*)&As[w * 16 + m][kb * 32 + quad * 8];
      #pragma unroll
      for (int nt = 0; nt < 4; ++nt) {
        short8 bb = *(const short8*)&Bs[nt * 16 + m][kb * 32 + quad * 8];
        acc[nt] = __builtin_amdgcn_mfma_f32_16x16x32_bf16(a, bb, acc[nt], 0, 0, 0);
      }
    }
  }
  #pragma unroll
  for (int nt = 0; nt < 4; ++nt)
    #pragma unroll
    for (int r = 0; r < 4; ++r) {
      int row = m0 + w * 16 + quad * 4 + r, col = n0 + nt * 16 + m;
      out[(size_t)row * 256 + col] = fmaxf(acc[nt][r] + gb[col], 0.f);
    }
}

// ---------------- grouped 1x1 conv + relu (fp32), dual write w/ diag seed ----------------
// out = relu(conv); out2 = relu(conv) * (seedbase + 0.25*[smask==0])
__global__ __launch_bounds__(256) void conv_kernel(
    const float* __restrict__ x, const float* __restrict__ w,
    const float* __restrict__ bias, const int* __restrict__ smask,
    float seedbase, float* __restrict__ out, float* __restrict__ out2) {
  __shared__ float Xs[64][65];
  __shared__ float Wsm[64][65];
  const int m0 = blockIdx.x * 64, g = blockIdx.y;
  const int tid = threadIdx.x, tx = tid & 15, ty = tid >> 4;
  #pragma unroll
  for (int l = 0; l < 16; ++l) {
    int idx = tid + l * 256; int r = idx >> 6, c = idx & 63;
    Xs[r][c] = x[(size_t)(m0 + r) * CH + g * DK + c];
    Wsm[r][c] = w[g * DK * DK + r * DK + c];
  }
  __syncthreads();
  float acc[4][4] = {};
  #pragma unroll 8
  for (int k = 0; k < DK; ++k) {
    float av[4], bv[4];
    #pragma unroll
    for (int i = 0; i < 4; ++i) av[i] = Xs[ty * 4 + i][k];
    #pragma unroll
    for (int j = 0; j < 4; ++j) bv[j] = Wsm[tx * 4 + j][k];
    #pragma unroll
    for (int i = 0; i < 4; ++i)
      #pragma unroll
      for (int j = 0; j < 4; ++j) acc[i][j] += av[i] * bv[j];
  }
  #pragma unroll
  for (int i = 0; i < 4; ++i) {
    int row = m0 + ty * 4 + i;
    float seed = seedbase + ((smask[row] == 0) ? 0.25f : 0.f);
    #pragma unroll
    for (int j = 0; j < 4; ++j) {
      int o = g * DK + tx * 4 + j;
      size_t idx = (size_t)row * CH + o;
      float v = fmaxf(acc[i][j] + bias[o], 0.f);
      out[idx] = v;
      out2[idx] = v * seed;
    }
  }
}

// ---------------- per-node per-head reciprocal L2 norms ----------------
__global__ void norms_kernel(const float* __restrict__ x, float* __restrict__ rn) {
  int bn = blockIdx.x;
  int t = threadIdx.x;
  float v = x[(size_t)bn * CH + t];
  float s = v * v;
  #pragma unroll
  for (int off = 32; off; off >>= 1) s += __shfl_down(s, off, 64);
  if ((t & 63) == 0) rn[bn * HEADS + (t >> 6)] = 1.0f / fmaxf(sqrtf(s), 1e-4f);
}

// top-4 insert, jax-stable tie-break (higher value first; equal value -> lower index)
__device__ inline void ins4(float v, int id, float tv[4], int tj[4]) {
  if (v < tv[3] || (v == tv[3] && id > tj[3])) return;
  tv[3] = v; tj[3] = id;
  #pragma unroll
  for (int k = 3; k > 0; --k) {
    bool sw = (tv[k] > tv[k - 1]) || (tv[k] == tv[k - 1] && tj[k] < tj[k - 1]);
    if (sw) {
      float fv = tv[k]; tv[k] = tv[k - 1]; tv[k - 1] = fv;
      int ti = tj[k]; tj[k] = tj[k - 1]; tj[k - 1] = ti;
    }
  }
}

// ---------------- per-row top-4 within a 256-col j-chunk (bf16 MFMA) ----------------
// Ranking: v = relu(dot * rnj) -- same order & zero-ties as relu(dot/(ni*nj)).
__global__ __launch_bounds__(256) void topk_part_kernel(
    const float* __restrict__ x, const float* __restrict__ rn,
    float* __restrict__ candV, int* __restrict__ candI) {
  __shared__ __align__(16) float cV[64][65];     // overlaid: Xj tile during j-loop
  __shared__ unsigned short cI[64][66];
  bf (*Xj)[LDK] = (bf(*)[LDK])cV;                // 9216 B <= 16640 B, safe overlay
  const int b = blockIdx.z, h = blockIdx.y;
  const int it = blockIdx.x >> 2, jc = blockIdx.x & 3;
  const int i0 = it * 64;
  const int tid = threadIdx.x, lane = tid & 63, w = tid >> 6;
  const int m = lane & 15, quad = lane >> 4;

  short8 afrag[2];
  load_afrag(&x[((size_t)b * NUM + i0 + w * 16 + m) * CH + h * DK], quad, afrag);

  float tv[4][4]; int tj[4][4];
  #pragma unroll
  for (int r = 0; r < 4; ++r)
    #pragma unroll
    for (int q = 0; q < 4; ++q) { tv[r][q] = -1.f; tj[r][q] = 0xffff; }

  for (int jt = 0; jt < 4; ++jt) {
    int j0 = jc * 256 + jt * 64;
    __syncthreads();
    stage_tile(x, (size_t)b * NUM + j0, h * DK, CH, Xj, tid);
    __syncthreads();
    #pragma unroll
    for (int nt = 0; nt < 4; ++nt) {
      f32x4 acc = {0.f, 0.f, 0.f, 0.f};
      #pragma unroll
      for (int kb = 0; kb < 2; ++kb) {
        short8 bb = *(const short8*)&Xj[nt * 16 + m][kb * 32 + quad * 8];
        acc = __builtin_amdgcn_mfma_f32_16x16x32_bf16(afrag[kb], bb, acc, 0, 0, 0);
      }
      int j = j0 + nt * 16 + m;
      float rnj = rn[((size_t)b * NUM + j) * HEADS + h];
      #pragma unroll
      for (int r = 0; r < 4; ++r) {
        float v = fmaxf(acc[r] * rnj, 0.f);
        ins4(v, j, tv[r], tj[r]);
      }
    }
  }
  __syncthreads();  // Xj dead; reuse memory as cV/cI
  #pragma unroll
  for (int r = 0; r < 4; ++r)
    #pragma unroll
    for (int q = 0; q < 4; ++q) {
      cV[w * 16 + quad * 4 + r][m * 4 + q] = tv[r][q];
      cI[w * 16 + quad * 4 + r][m * 4 + q] = (unsigned short)tj[r][q];
    }
  __syncthreads();
  if (tid < 64) {
    float fv[4] = {-1.f, -1.f, -1.f, -1.f};
    int fi[4] = {0x7fffffff, 0x7fffffff, 0x7fffffff, 0x7fffffff};
    for (int q = 0; q < 64; ++q) ins4(cV[tid][q], (int)cI[tid][q], fv, fi);
    size_t base = (size_t)((((b * HEADS + h) * 16 + it) * NJC + jc) * 64 + tid) * 4;
    #pragma unroll
    for (int q = 0; q < 4; ++q) { candV[base + q] = fv[q]; candI[base + q] = fi[q]; }
  }
}

// ---------------- merge NJC chunk candidates per row -> union into vec ----------------
__global__ __launch_bounds__(256) void topk_merge_kernel(
    const float* __restrict__ candV, const int* __restrict__ candI,
    float* __restrict__ vec) {
  int t = blockIdx.x * 256 + threadIdx.x;   // t = bhit*64 + rl
  int bhit = t >> 6, rl = t & 63;
  float fv[4] = {-1.f, -1.f, -1.f, -1.f};
  int fi[4] = {0x7fffffff, 0x7fffffff, 0x7fffffff, 0x7fffffff};
  #pragma unroll
  for (int jc = 0; jc < NJC; ++jc) {
    size_t base = (size_t)(((bhit) * NJC + jc) * 64 + rl) * 4;
    #pragma unroll
    for (int q = 0; q < 4; ++q) ins4(candV[base + q], candI[base + q], fv, fi);
  }
  #pragma unroll
  for (int q = 0; q < 4; ++q) vec[fi[q]] = 1.0f;  // benign race, all write 1
}

// ---------------- masked attention apply (bf16 MFMA scores + PV), j-chunked ----------------
// Ws[i][j] = pkbit(i,j) * relu(cos_ij)*0.25 ; PV uses vec-masked conv^T tile.
// Diagonal f_mask term is pre-seeded into `out` by conv_kernel.
// Per-wave Ws stripe: scores->PV needs no barrier (same-wave LDS ordering).
__global__ __launch_bounds__(256) void apply_kernel(
    const float* __restrict__ x, const float* __restrict__ conv,
    float* __restrict__ out, const float* __restrict__ rn,
    const float* __restrict__ vec, const u64* __restrict__ pk) {
  __shared__ __align__(16) bf Xj[64][LDK];
  __shared__ __align__(16) bf Cv[64][LDK];
  __shared__ __align__(16) bf Ws[64][LDK];
  const int b = blockIdx.z, h = blockIdx.y;
  const int it = blockIdx.x >> 2, jc = blockIdx.x & 3;
  const int i0 = it * 64;
  const int tid = threadIdx.x, lane = tid & 63, w = tid >> 6;
  const int m = lane & 15, quad = lane >> 4;

  short8 afrag[2];
  load_afrag(&x[((size_t)b * NUM + i0 + w * 16 + m) * CH + h * DK], quad, afrag);

  float rni4[4];
  #pragma unroll
  for (int r = 0; r < 4; ++r) {
    int row = i0 + w * 16 + quad * 4 + r;
    rni4[r] = 0.25f * rn[((size_t)b * NUM + row) * HEADS + h];
  }
  f32x4 om[4] = {{0.f,0.f,0.f,0.f},{0.f,0.f,0.f,0.f},{0.f,0.f,0.f,0.f},{0.f,0.f,0.f,0.f}};

  for (int jt = 0; jt < 4; ++jt) {
    int j0 = jc * 256 + jt * 64;
    __syncthreads();   // protect Xj/Cv from previous iteration's readers
    stage_tile(x, (size_t)b * NUM + j0, h * DK, CH, Xj, tid);
    {  // vec-masked conv^T tile
      int jr = tid >> 4, c4 = tid & 15;
      #pragma unroll
      for (int itt = 0; itt < 4; ++itt) {
        int j = jr + itt * 16;
        float vm = vec[j0 + j];
        const float4 v = *(const float4*)&conv[((size_t)b * NUM + j0 + j) * CH + h * DK + c4 * 4];
        Cv[c4 * 4 + 0][j] = tobf(v.x * vm);
        Cv[c4 * 4 + 1][j] = tobf(v.y * vm);
        Cv[c4 * 4 + 2][j] = tobf(v.z * vm);
        Cv[c4 * 4 + 3][j] = tobf(v.w * vm);
      }
    }
    u64 wr[4];
    #pragma unroll
    for (int r = 0; r < 4; ++r)
      wr[r] = pk[((size_t)b * NUM + i0 + w * 16 + quad * 4 + r) * 16 + (j0 >> 6)];
    __syncthreads();
    // scores -> masked weights -> Ws (own wave's 16-row stripe only)
    #pragma unroll
    for (int nt = 0; nt < 4; ++nt) {
      f32x4 acc = {0.f, 0.f, 0.f, 0.f};
      #pragma unroll
      for (int kb = 0; kb < 2; ++kb) {
        short8 bb = *(const short8*)&Xj[nt * 16 + m][kb * 32 + quad * 8];
        acc = __builtin_amdgcn_mfma_f32_16x16x32_bf16(afrag[kb], bb, acc, 0, 0, 0);
      }
      float rnj = rn[((size_t)b * NUM + j0 + nt * 16 + m) * HEADS + h];
      #pragma unroll
      for (int r = 0; r < 4; ++r) {
        float a = fmaxf(acc[r] * rni4[r] * rnj, 0.f);
        bool bit = (wr[r] >> (nt * 16 + m)) & 1ull;
        Ws[w * 16 + quad * 4 + r][nt * 16 + m] = tobf(bit ? a : 0.f);
      }
    }
    // PV: same-wave Ws stripe + Cv (stable until next loop-top barrier)
    #pragma unroll
    for (int kb = 0; kb < 2; ++kb) {
      short8 a = *(const short8*)&Ws[w * 16 + m][kb * 32 + quad * 8];
      #pragma unroll
      for (int ct = 0; ct < 4; ++ct) {
        short8 bb = *(const short8*)&Cv[ct * 16 + m][kb * 32 + quad * 8];
        om[ct] = __builtin_amdgcn_mfma_f32_16x16x32_bf16(a, bb, om[ct], 0, 0, 0);
      }
    }
  }
  #pragma unroll
  for (int ct = 0; ct < 4; ++ct)
    #pragma unroll
    for (int r = 0; r < 4; ++r) {
      size_t idx = ((size_t)b * NUM + i0 + w * 16 + quad * 4 + r) * CH + h * DK + ct * 16 + m;
      atomicAdd(&out[idx], om[ct][r]);
    }
}

// ---------------- LayerNorm + final outputs (in-place on d_out regions) ----------------
__global__ __launch_bounds__(256) void final_kernel(
    float* __restrict__ ybnf, float* __restrict__ out0,
    const float* __restrict__ lnw, const float* __restrict__ lnb) {
  __shared__ float r1[4];
  __shared__ float r2[4];
  int bn = blockIdx.x;
  int c = threadIdx.x;
  size_t idx = (size_t)bn * CH + c;
  float y = ybnf[idx];
  float x2v = out0[idx];
  float s = y;
  #pragma unroll
  for (int off = 32; off; off >>= 1) s += __shfl_down(s, off, 64);
  int wave = c >> 6, lane = c & 63;
  if (lane == 0) r1[wave] = s;
  __syncthreads();
  float mu = (r1[0] + r1[1] + r1[2] + r1[3]) * (1.f / 256.f);
  float d = y - mu;
  float s2 = d * d;
  #pragma unroll
  for (int off = 32; off; off >>= 1) s2 += __shfl_down(s2, off, 64);
  if (lane == 0) r2[wave] = s2;
  __syncthreads();
  float var = (r2[0] + r2[1] + r2[2] + r2[3]) * (1.f / 256.f);
  float nf = d * rsqrtf(var + 1e-6f) * lnw[c] + lnb[c];
  ybnf[idx] = nf;
  out0[idx] = x2v + nf;
}

extern "C" void kernel_launch(void* const* d_in, const int* in_sizes, int n_in,
                              void* d_out, int out_size, void* d_ws, size_t ws_size,
                              hipStream_t stream) {
  const float* input = (const float*)d_in[0];
  const int* mroi = (const int*)d_in[1];
  const int* smask = (const int*)d_in[2];
  const float* gt_feat = (const float*)d_in[3];
  const float* w1 = (const float*)d_in[4];
  const float* b1 = (const float*)d_in[5];
  const float* w2 = (const float*)d_in[6];
  const float* b2 = (const float*)d_in[7];
  const float* gt_w = (const float*)d_in[8];
  const float* gt_b = (const float*)d_in[9];
  const float* lnw = (const float*)d_in[10];
  const float* lnb = (const float*)d_in[11];

  const size_t SEG = (size_t)B_ * NUM * CH;  // 1048576 elements
  float* out0 = (float*)d_out;     // finally: out2^T + node_feat ; interim: X2 (conv2)
  float* gts = out0 + SEG;         // gts output (final from the start)
  float* nfreg = out0 + 2 * SEG;   // finally: node_feat ; interim: X1 then Yb

  // ws: F1 4MB | RN 64KB | VECF 8KB | candV 1MB | candI 1MB | PK 512KB ~= 6.9 MB
  float* F1 = (float*)d_ws;
  float* RN = F1 + SEG;
  float* VEC1 = RN + (size_t)B_ * NUM * HEADS;
  float* VEC2 = VEC1 + NUM;
  float* candV = VEC2 + NUM;
  int* candI = (int*)(candV + (size_t)B_ * HEADS * 16 * NJC * 64 * 4);
  u64* PK = (u64*)(candI + (size_t)B_ * HEADS * 16 * NJC * 64 * 4);

  float* X1 = nfreg;  // conv1 output (F1 seeded = X1*(1+0.25*[sm==0]))
  float* X2 = out0;   // conv2 output lives in out0 region until final_kernel
  float* Yb = nfreg;  // o2m accumulator (seeded = 0.25*[sm==0]*X2, overwrites dead X1)

  zero_vec_kernel<<<4, 256, 0, stream>>>(VEC1, VEC2);
  pack_kernel<<<1024, 256, 0, stream>>>(mroi, smask, PK);
  gts_kernel<<<dim3(64, 4), 256, 0, stream>>>(gt_feat, gt_w, gt_b, gts);

  // stage 1
  conv_kernel<<<dim3(64, 4), 256, 0, stream>>>(input, w1, b1, smask, 1.0f, X1, F1);
  norms_kernel<<<4096, 256, 0, stream>>>(input, RN);
  topk_part_kernel<<<dim3(64, HEADS, B_), 256, 0, stream>>>(input, RN, candV, candI);
  topk_merge_kernel<<<64, 256, 0, stream>>>(candV, candI, VEC1);
  apply_kernel<<<dim3(64, HEADS, B_), 256, 0, stream>>>(
      input, X1, F1, RN, VEC1, PK);

  // stage 2
  conv_kernel<<<dim3(64, 4), 256, 0, stream>>>(F1, w2, b2, smask, 0.0f, X2, Yb);
  norms_kernel<<<4096, 256, 0, stream>>>(F1, RN);
  topk_part_kernel<<<dim3(64, HEADS, B_), 256, 0, stream>>>(F1, RN, candV, candI);
  topk_merge_kernel<<<64, 256, 0, stream>>>(candV, candI, VEC2);
  apply_kernel<<<dim3(64, HEADS, B_), 256, 0, stream>>>(
      F1, X2, Yb, RN, VEC2, PK);

  final_kernel<<<4096, 256, 0, stream>>>(Yb, X2, lnw, lnb);
}